// Round 11
// baseline (174.184 us; speedup 1.0000x reference)
//
#include <hip/hip_runtime.h>
#include <math.h>

// Problem constants: B molecules, N=64 atoms, E=512 edges, R_CUT=10
#define SQRT_PI 1.7724538509055160273
#define SQRT_2  1.4142135623730950488
#define PI_OVER_2RC 0.15707963267948966

typedef double dbl4 __attribute__((ext_vector_type(4)));

// ws layout (doubles): flags fl[0..4] only.

__device__ __forceinline__ double bcast64(double v, int lane) {
    union { double d; unsigned int u[2]; } a, r;
    a.d = v;
    r.u[0] = __builtin_amdgcn_readlane(a.u[0], lane);
    r.u[1] = __builtin_amdgcn_readlane(a.u[1], lane);
    return r.d;
}

__device__ __forceinline__ double a_entry(int i, int j, const double* posd,
                                          const double* sig, const double* dg) {
    if (i == j) return dg[i];
    double dx = posd[3*i+0]-posd[3*j+0];
    double dy = posd[3*i+1]-posd[3*j+1];
    double dz = posd[3*i+2]-posd[3*j+2];
    double d  = sqrt(dx*dx+dy*dy+dz*dz);
    double g  = sqrt(sig[i]+sig[j]);
    return erf(d/(SQRT_2*g))/d;
}

// swap-aware MFMA: xv = A-side value, yv = B-side value
__device__ __forceinline__ dbl4 mfma64(int cS, double xv, double yv, dbl4 acc) {
    return cS ? __builtin_amdgcn_mfma_f64_16x16x4f64(yv, xv, acc, 0, 0, 0)
              : __builtin_amdgcn_mfma_f64_16x16x4f64(xv, yv, acc, 0, 0, 0);
}

// ---------------- K0: f64-MFMA layout probe (injective, dual value-set) ----------------
__global__ __launch_bounds__(64)
void k0_probe(double* __restrict__ fl)
{
    const int l = threadIdx.x;
    const int kl = l >> 4, ml = l & 15;
    const double af1 = (double)(l + 1),  bf1 = (double)(l + 65);
    const double af2 = (double)(1 + ((l*7 + 3) % 61));
    const double bf2 = (double)(2 + ((l*13 + 5) % 53));
    dbl4 c1 = {0.0,0.0,0.0,0.0}, c2 = {0.0,0.0,0.0,0.0};
    c1 = __builtin_amdgcn_mfma_f64_16x16x4f64(af1, bf1, c1, 0, 0, 0);
    c2 = __builtin_amdgcn_mfma_f64_16x16x4f64(af2, bf2, c2, 0, 0, 0);
    int best = -1;
    for (int h = 0; h < 32; ++h) {
        if (best >= 0) break;
        const int cS = h >> 4, cA = (h >> 3) & 1, cB = (h >> 2) & 1, cD = h & 3;
        bool ok = true;
        #pragma unroll
        for (int r = 0; r < 4; ++r) {
            int row, col;
            const int v0 = 4*kl + r, v1 = kl + 4*r;
            if (cD == 0)      { row = v0; col = ml; }
            else if (cD == 1) { row = v1; col = ml; }
            else if (cD == 2) { row = ml; col = v0; }
            else              { row = ml; col = v1; }
            double r1 = 0.0, r2 = 0.0;
            #pragma unroll
            for (int k = 0; k < 4; ++k) {
                const int la = cA ? (row*4 + k) : (row + 16*k);
                const int lb = cB ? (col*4 + k) : (col + 16*k);
                if (cS == 0) {
                    r1 += (double)(la + 1) * (double)(lb + 65);
                    r2 += (double)(1 + ((la*7+3) % 61)) * (double)(2 + ((lb*13+5) % 53));
                } else {
                    r1 += (double)(lb + 1) * (double)(la + 65);
                    r2 += (double)(1 + ((lb*7+3) % 61)) * (double)(2 + ((la*13+5) % 53));
                }
            }
            if (c1[r] != r1 || c2[r] != r2) ok = false;
        }
        if (__ballot(ok) == ~0ull) best = h;
    }
    if (l == 0) {
        fl[0] = (best >= 0) ? 1.0 : 0.0;
        fl[1] = (double)((best >= 0) ? (best >> 4)      : 0);
        fl[2] = (double)((best >= 0) ? ((best >> 3) & 1) : 0);
        fl[3] = (double)((best >= 0) ? ((best >> 2) & 1) : 0);
        fl[4] = (double)((best >= 0) ? (best & 3)        : 0);
    }
}

// ---------------- fused kernel ----------------
// one block (16 waves) per molecule.  BASE = round-10 verified structure
// (75.7 us).  ONE change vs round 10:
//   Double-buffered single-factor gram: w>0 always, so S = C C^T with
//   C = T*diag(sqrt(w)).  Two 64-edge ping-pong buffers Cd0/Cd1 in the SAME
//   LDS that Ta/Tb used.  Iteration cc stages chunk cc+1 into buf[(cc+1)&1]
//   while MFMA reads buf[cc&1] -> ONE barrier per chunk (gram barriers
//   16 -> 10 incl. prologue), staging writes halved (2 ds_write_b128),
//   stage latency hidden under the MFMA window.  t0b = (T*sqrt(w))*sqrt(w).
// k-range tile split (round 10, verified neutral) kept.
// Identity 1: out = u; Identity 2: sa.t0b = ua.gb, sb.t0b = ub.gb.
// Lambda via lam_sh + barrier (in-register bcast of conditionally-assigned
// value miscompiled in round 5).
__global__ __launch_bounds__(1024)
void k_fused(const float* __restrict__ pos, const float* __restrict__ T,
             const int* __restrict__ eidx, const float* __restrict__ nattr,
             const float* __restrict__ eneg, const float* __restrict__ qtot,
             const float* __restrict__ hard, const float* __restrict__ covr,
             const int* __restrict__ an, const double* __restrict__ flq,
             float* __restrict__ outp)
{
    const int m = blockIdx.x, tid = threadIdx.x;
    const int jl = tid & 63;        // lane
    const int rg = tid >> 6;        // wave id 0..15
    const int kl = jl >> 4, ml = jl & 15;

    __shared__ double R[2*64*66];   // Cd0,Cd1 | SB,Pm   (67584 B)
    __shared__ double AB[64*65];    // A then M/L        (33280 B)
    __shared__ double w_sl[512];    // w
    __shared__ double rw_sl[512];   // sqrt(w)
    __shared__ double posd[192], sig_s[64], dg_s[64], eneg_s[64];
    __shared__ double t0a_s[64], t0b_s[64], ga_s[64], gb_s[64];
    __shared__ double ua_s[64], ub_s[64];
    __shared__ double dinv_s[64], dvec_s[64];
    __shared__ double lam_sh, sw_sh;

    double* const Cd0 = R;          // [64][66] f64, gram ping buffer
    double* const Cd1 = R + 64*66;  // [64][66] f64, gram pong buffer
    double* const SB = R;           // [64][66] f64, S (post-gram .. end)
    double* const Pm = R + 64*66;   // [64][66] f64, P = A*S

    // probed MFMA layout (k0 ran before us; deterministic)
    const int cS = (int)flq[1], cA = (int)flq[2], cB = (int)flq[3], cD = (int)flq[4];
    const int aRow = cA ? (jl >> 2) : ml;
    const int aK   = cA ? (jl & 3)  : kl;
    const int bRow = cB ? (jl >> 2) : ml;
    const int bK   = cB ? (jl & 3)  : kl;
    int drow[4], dcol[4];
    #pragma unroll
    for (int r = 0; r < 4; ++r) {
        const int v0 = 4*kl + r, v1 = kl + 4*r;
        if (cD == 0)      { drow[r] = v0; dcol[r] = ml; }
        else if (cD == 1) { drow[r] = v1; dcol[r] = ml; }
        else if (cD == 2) { drow[r] = ml; dcol[r] = v0; }
        else              { drow[r] = ml; dcol[r] = v1; }
    }

    const float* Tm = T + (size_t)m*64*512;
    const int srow = tid >> 4, sc4 = (tid & 15) * 4;

    // earliest possible chunk-0 prefetch
    float4 v = *(const float4*)&Tm[srow*512 + sc4];

    // ---- phase A: per-atom loads ----
    if (tid < 64) {
        posd[3*tid+0] = (double)pos[(m*64+tid)*3+0];
        posd[3*tid+1] = (double)pos[(m*64+tid)*3+1];
        posd[3*tid+2] = (double)pos[(m*64+tid)*3+2];
        double r = (double)covr[an[m*64+tid]];
        sig_s[tid] = r*r;
        const float* np_ = nattr + (size_t)(m*64+tid)*10;
        float best = np_[0]; int bi = 0;
        #pragma unroll
        for (int k = 1; k < 10; ++k) { float vv = np_[k]; if (vv > best) { best = vv; bi = k; } }
        dg_s[tid] = (double)hard[bi] + 1.0/(SQRT_PI*r);
    } else if (tid < 128) {
        int ll = tid - 64;
        eneg_s[ll] = (double)eneg[m*64 + ll];
    }
    __syncthreads();

    // ---- phase B: edge weights w, sqrt(w) (tid<512) ----
    if (tid < 512) {
        const int a0 = eidx[(size_t)m*1024 + tid];
        const int a1 = eidx[(size_t)m*1024 + 512 + tid];
        double dx = posd[3*a0+0]-posd[3*a1+0];
        double dy = posd[3*a0+1]-posd[3*a1+1];
        double dz = posd[3*a0+2]-posd[3*a1+2];
        double d  = sqrt(dx*dx+dy*dy+dz*dz);
        double w  = 1.0 / (1.0/cos(PI_OVER_2RC*d) - 1.0);
        w_sl[tid]  = w;
        rw_sl[tid] = sqrt(w);
    }
    __syncthreads();   // rw visible for prologue staging

    // ---- Gram work assignment: 10 tiles, diag waves {0,5,10,15} full-k,
    //      off-diag pairs split by k-range. wm: 0=kk 0..15, 1=kk 0..7, 2=kk 8..15.
    int tp, tq, wm;
    switch (rg) {
        case 0:  tp=0; tq=0; wm=0; break;
        case 5:  tp=1; tq=1; wm=0; break;
        case 10: tp=2; tq=2; wm=0; break;
        case 15: tp=3; tq=3; wm=0; break;
        case 1:  tp=1; tq=0; wm=1; break;
        case 2:  tp=1; tq=0; wm=2; break;
        case 3:  tp=2; tq=0; wm=1; break;
        case 4:  tp=2; tq=0; wm=2; break;
        case 6:  tp=2; tq=1; wm=1; break;
        case 7:  tp=2; tq=1; wm=2; break;
        case 8:  tp=3; tq=0; wm=1; break;
        case 9:  tp=3; tq=0; wm=2; break;
        case 11: tp=3; tq=1; wm=1; break;
        case 12: tp=3; tq=1; wm=2; break;
        case 13: tp=3; tq=2; wm=1; break;
        default: tp=3; tq=2; wm=2; break;   // rg == 14
    }
    const double* ca_b = &Cd0[(size_t)(tp*16 + aRow)*66 + aK];
    const double* cb_b = &Cd0[(size_t)(tq*16 + bRow)*66 + bK];
    dbl4 vacc = {0.0, 0.0, 0.0, 0.0};
    double t0b_p = 0.0;
    double areg[4];

    // ---- prologue: stage chunk 0 into Cd0, prefetch chunk 1 ----
    {
        const double r0 = rw_sl[sc4+0], r1 = rw_sl[sc4+1];
        const double r2 = rw_sl[sc4+2], r3 = rw_sl[sc4+3];
        const double c0 = (double)v.x*r0, c1 = (double)v.y*r1;
        const double c2 = (double)v.z*r2, c3 = (double)v.w*r3;
        double2 p0; p0.x = c0; p0.y = c1;
        double2 p1; p1.x = c2; p1.y = c3;
        *(double2*)&Cd0[srow*66 + sc4]     = p0;
        *(double2*)&Cd0[srow*66 + sc4 + 2] = p1;
        t0b_p += c0*r0 + c1*r1 + c2*r2 + c3*r3;
        v = *(const float4*)&Tm[srow*512 + 64 + sc4];
    }
    __syncthreads();   // Cd0 (chunk 0) visible

    #pragma unroll
    for (int cc = 0; cc < 8; ++cc) {
        // stage chunk cc+1 into the other buffer (overlaps this chunk's MFMA)
        if (cc < 7) {
            const int e = (cc+1)*64 + sc4;
            const double r0 = rw_sl[e+0], r1 = rw_sl[e+1];
            const double r2 = rw_sl[e+2], r3 = rw_sl[e+3];
            const double c0 = (double)v.x*r0, c1 = (double)v.y*r1;
            const double c2 = (double)v.z*r2, c3 = (double)v.w*r3;
            double* Cw = (((cc+1) & 1) ? Cd1 : Cd0);
            double2 p0; p0.x = c0; p0.y = c1;
            double2 p1; p1.x = c2; p1.y = c3;
            *(double2*)&Cw[srow*66 + sc4]     = p0;
            *(double2*)&Cw[srow*66 + sc4 + 2] = p1;
            t0b_p += c0*r0 + c1*r1 + c2*r2 + c3*r3;
            if (cc < 6) v = *(const float4*)&Tm[srow*512 + (cc+2)*64 + sc4];
        }
        if (cc == 0 && tid >= 128 && tid < 192) {  // wave2: sum(w) (cheap, once)
            const int ll = tid - 128;
            double s = 0.0;
            #pragma unroll
            for (int c = 0; c < 8; ++c) s += w_sl[c*64 + ll];
            #pragma unroll
            for (int off = 32; off > 0; off >>= 1) s += __shfl_down(s, off);
            if (ll == 0) sw_sh = s;
        }
        if (cc < 4) {                              // A-build under MFMA shadow
            const int i = rg + 16*cc;
            double av = a_entry(i, jl, posd, sig_s, dg_s);
            areg[cc] = av;
            AB[i*65 + jl] = av;
        }
        const int bo = (cc & 1) * 4224;            // current buffer offset
        if (wm == 0) {
            #pragma unroll
            for (int kk = 0; kk < 16; ++kk)
                vacc = mfma64(cS, ca_b[bo + kk*4], cb_b[bo + kk*4], vacc);
        } else if (wm == 1) {
            #pragma unroll
            for (int kk = 0; kk < 8; ++kk)
                vacc = mfma64(cS, ca_b[bo + kk*4], cb_b[bo + kk*4], vacc);
        } else {
            #pragma unroll
            for (int kk = 8; kk < 16; ++kk)
                vacc = mfma64(cS, ca_b[bo + kk*4], cb_b[bo + kk*4], vacc);
        }
        __syncthreads();   // reads of buf[cc&1] done; staged chunk cc+1 visible
    }
    // last loop barrier doubles as the gram->SB transition barrier

    // ---- S assembly: full/first-half writers first, second-half adders second ----
    if (wm != 2) {
        #pragma unroll
        for (int r = 0; r < 4; ++r) {
            const int ri = tp*16 + drow[r], cj = tq*16 + dcol[r];
            SB[ri*66 + cj] = vacc[r];
            if (tp != tq) SB[cj*66 + ri] = vacc[r];
        }
    }
    {   // t0b: reduce 16 column-group partials per row (register-only)
        double t = t0b_p;
        t += __shfl_down(t, 8, 16);
        t += __shfl_down(t, 4, 16);
        t += __shfl_down(t, 2, 16);
        t += __shfl_down(t, 1, 16);
        if ((tid & 15) == 0) t0b_s[tid >> 4] = t;
    }
    __syncthreads();
    if (wm == 2) {
        #pragma unroll
        for (int r = 0; r < 4; ++r) {
            const int ri = tp*16 + drow[r], cj = tq*16 + dcol[r];
            const double vv = vacc[r];
            SB[ri*66 + cj] += vv;
            if (tp != tq) SB[cj*66 + ri] += vv;
        }
    }
    __syncthreads();   // S complete

    // ---- t0a = -S·eneg (LDS-S, 16-lane reduce) ----
    {
        const int c16 = tid & 15, row16 = tid >> 4;
        double a = 0.0;
        #pragma unroll
        for (int kk = 0; kk < 4; ++kk)
            a += SB[row16*66 + 4*c16 + kk] * eneg_s[4*c16 + kk];
        a += __shfl_down(a, 8, 16);
        a += __shfl_down(a, 4, 16);
        a += __shfl_down(a, 2, 16);
        a += __shfl_down(a, 1, 16);
        if (c16 == 0) t0a_s[row16] = -a;
    }
    __syncthreads();

    // ---- g = A·t0 via areg wave reduction ----
    {
        double ra[4], rb[4];
        const double ta = t0a_s[jl], tb = t0b_s[jl];
        #pragma unroll
        for (int p = 0; p < 4; ++p) { ra[p] = areg[p]*ta; rb[p] = areg[p]*tb; }
        #pragma unroll
        for (int off = 32; off > 0; off >>= 1) {
            #pragma unroll
            for (int p = 0; p < 4; ++p) {
                ra[p] += __shfl_down(ra[p], off);
                rb[p] += __shfl_down(rb[p], off);
            }
        }
        if (jl == 0) {
            #pragma unroll
            for (int p = 0; p < 4; ++p) { ga_s[rg+16*p] = ra[p]; gb_s[rg+16*p] = rb[p]; }
        }
    }
    __syncthreads();

    // ---- GEMM1: P = A·S (16 tiles / 16 waves, immediate-offset operands) ----
    const int ti = rg >> 2, tj = rg & 3;
    {
        const double* xb = &AB[(size_t)(ti*16 + aRow)*65 + aK];
        const double* yb = &SB[(size_t)bK*66 + tj*16 + bRow];
        dbl4 pacc = {0.0, 0.0, 0.0, 0.0};
        #pragma unroll
        for (int kk = 0; kk < 16; ++kk)
            pacc = mfma64(cS, xb[kk*4], yb[kk*264], pacc);
        #pragma unroll
        for (int r = 0; r < 4; ++r)
            Pm[(ti*16 + drow[r])*66 + tj*16 + dcol[r]] = pacc[r];   // Pm != SB, no barrier needed
    }
    __syncthreads();   // P visible

    // ---- GEMM2: M = A + P·A, overwrite AB ----
    {
        dbl4 macc;
        #pragma unroll
        for (int r = 0; r < 4; ++r)
            macc[r] = AB[(ti*16 + drow[r])*65 + tj*16 + dcol[r]];
        const double* xb = &Pm[(size_t)(ti*16 + aRow)*66 + aK];
        const double* yb = &AB[(size_t)bK*65 + tj*16 + bRow];
        #pragma unroll
        for (int kk = 0; kk < 16; ++kk)
            macc = mfma64(cS, xb[kk*4], yb[kk*260], macc);
        __syncthreads();   // all GEMM2 AB reads done
        #pragma unroll
        for (int r = 0; r < 4; ++r)
            AB[(ti*16 + drow[r])*65 + tj*16 + dcol[r]] = macc[r];
    }
    __syncthreads();

    // ---- blocked LDL^T: wave0 panel factor + trailing updates (verified) ----
    for (int pb = 0; pb < 4; ++pb) {
        const int kb = pb*16;
        if (tid < 64) {
            const int i = tid;
            double pr[16];
            #pragma unroll
            for (int c = 0; c < 16; ++c) pr[c] = AB[i*65 + kb + c];
            #pragma unroll
            for (int c = 0; c < 16; ++c) {
                const int k = kb + c;
                const double Dk = bcast64(pr[c], k);
                const double di = 1.0 / Dk;
                if (i == k) { dinv_s[k] = di; dvec_s[k] = Dk; }
                const double lik = pr[c] * di;
                #pragma unroll
                for (int j = c+1; j < 16; ++j) {
                    const double mkj = bcast64(pr[j], k);
                    if (i > k) pr[j] -= lik * mkj;
                }
                if (i > k) pr[c] = lik;
            }
            #pragma unroll
            for (int c = 0; c < 16; ++c) AB[i*65 + kb + c] = pr[c];
        }
        __syncthreads();
        const int lim = kb + 16;
        if (lim < 64) {
            double tacc[4] = {0.0, 0.0, 0.0, 0.0};
            #pragma unroll 4
            for (int c = 0; c < 16; ++c) {
                double lbv = AB[jl*65 + kb + c] * dvec_s[kb + c];
                #pragma unroll
                for (int p = 0; p < 4; ++p)
                    tacc[p] += AB[(rg+16*p)*65 + kb + c] * lbv;
            }
            if (jl >= lim) {
                #pragma unroll
                for (int p = 0; p < 4; ++p) {
                    int i = rg + 16*p;
                    if (i >= lim) AB[i*65 + jl] -= tacc[p];
                }
            }
        }
        __syncthreads();
    }

    // ---- solves: wave0 does RHS a, wave1 does RHS b (independent chains) ----
    if (tid < 128) {
        const int i = jl;
        double h = (rg == 0) ? ga_s[i] : gb_s[i];
        #pragma unroll
        for (int j = 0; j < 63; ++j) {
            double x = bcast64(h, j);
            double lij = (i > j) ? AB[i*65+j] : 0.0;
            h -= lij*x;
        }
        h *= dinv_s[i];
        #pragma unroll
        for (int j = 63; j > 0; --j) {
            double x = bcast64(h, j);
            double lji = (i < j) ? AB[j*65+i] : 0.0;
            h -= lji*x;
        }
        if (rg == 0) ua_s[i] = h; else ub_s[i] = h;
    }
    __syncthreads();

    // ---- lambda (identities: sa.t0b = ua.gb, sb.t0b = ub.gb), via lam_sh ----
    if (tid < 64) {
        const double ua = ua_s[tid], ub = ub_s[tid], gbv = gb_s[tid];
        double d1 = eneg_s[tid]*t0b_s[tid] + ua*gbv;   // = (eneg + sa)·t0b termwise
        double d2 = ub*gbv;                            // = sb·t0b termwise
        #pragma unroll
        for (int off = 32; off > 0; off >>= 1) {
            d1 += __shfl_down(d1, off);
            d2 += __shfl_down(d2, off);
        }
        if (tid == 0) {
            double sY = -d1;
            double sZ = sw_sh - d2;
            lam_sh = ((double)qtot[m] - sY) / (1.0 - sZ);
        }
    }
    __syncthreads();
    if (tid < 64)
        outp[m*64 + tid] = (float)(ua_s[tid] - lam_sh*ub_s[tid]);
}

extern "C" void kernel_launch(void* const* d_in, const int* in_sizes, int n_in,
                              void* d_out, int out_size, void* d_ws, size_t ws_size,
                              hipStream_t stream) {
    const float* pos  = (const float*)d_in[0];
    const float* T    = (const float*)d_in[1];
    const float* eneg = (const float*)d_in[2];
    const float* nat  = (const float*)d_in[3];
    const float* qt   = (const float*)d_in[4];
    // d_in[5] 'p' unused
    const float* hard = (const float*)d_in[6];
    const float* covr = (const float*)d_in[7];
    const int*   an   = (const int*)d_in[8];
    const int*   eidx = (const int*)d_in[9];
    float* outp = (float*)d_out;
    (void)n_in; (void)out_size; (void)ws_size;

    const int B = in_sizes[4];
    double* ws = (double*)d_ws;   // 5 doubles (probe flags)

    k0_probe<<<dim3(1), dim3(64), 0, stream>>>(ws);
    k_fused<<<dim3(B), dim3(1024), 0, stream>>>(pos, T, eidx, nat, eneg, qt,
                                                hard, covr, an, ws, outp);
}

// Round 12
// 157.403 us; speedup vs baseline: 1.1066x; 1.1066x over previous
//
#include <hip/hip_runtime.h>
#include <math.h>

// Problem constants: B molecules, N=64 atoms, E=512 edges, R_CUT=10
#define SQRT_PI 1.7724538509055160273
#define SQRT_2  1.4142135623730950488
#define PI_OVER_2RC 0.15707963267948966

typedef double dbl4 __attribute__((ext_vector_type(4)));

// ws layout (doubles): flags fl[0..4] only.

__device__ __forceinline__ double bcast64(double v, int lane) {
    union { double d; unsigned int u[2]; } a, r;
    a.d = v;
    r.u[0] = __builtin_amdgcn_readlane(a.u[0], lane);
    r.u[1] = __builtin_amdgcn_readlane(a.u[1], lane);
    return r.d;
}

__device__ __forceinline__ double a_entry(int i, int j, const double* posd,
                                          const double* sig, const double* dg) {
    if (i == j) return dg[i];
    double dx = posd[3*i+0]-posd[3*j+0];
    double dy = posd[3*i+1]-posd[3*j+1];
    double dz = posd[3*i+2]-posd[3*j+2];
    double d  = sqrt(dx*dx+dy*dy+dz*dz);
    double g  = sqrt(sig[i]+sig[j]);
    return erf(d/(SQRT_2*g))/d;
}

// swap-aware MFMA: xv = A-side value, yv = B-side value
__device__ __forceinline__ dbl4 mfma64(int cS, double xv, double yv, dbl4 acc) {
    return cS ? __builtin_amdgcn_mfma_f64_16x16x4f64(yv, xv, acc, 0, 0, 0)
              : __builtin_amdgcn_mfma_f64_16x16x4f64(xv, yv, acc, 0, 0, 0);
}

// ---------------- K0: f64-MFMA layout probe (injective, dual value-set) ----------------
__global__ __launch_bounds__(64)
void k0_probe(double* __restrict__ fl)
{
    const int l = threadIdx.x;
    const int kl = l >> 4, ml = l & 15;
    const double af1 = (double)(l + 1),  bf1 = (double)(l + 65);
    const double af2 = (double)(1 + ((l*7 + 3) % 61));
    const double bf2 = (double)(2 + ((l*13 + 5) % 53));
    dbl4 c1 = {0.0,0.0,0.0,0.0}, c2 = {0.0,0.0,0.0,0.0};
    c1 = __builtin_amdgcn_mfma_f64_16x16x4f64(af1, bf1, c1, 0, 0, 0);
    c2 = __builtin_amdgcn_mfma_f64_16x16x4f64(af2, bf2, c2, 0, 0, 0);
    int best = -1;
    for (int h = 0; h < 32; ++h) {
        if (best >= 0) break;
        const int cS = h >> 4, cA = (h >> 3) & 1, cB = (h >> 2) & 1, cD = h & 3;
        bool ok = true;
        #pragma unroll
        for (int r = 0; r < 4; ++r) {
            int row, col;
            const int v0 = 4*kl + r, v1 = kl + 4*r;
            if (cD == 0)      { row = v0; col = ml; }
            else if (cD == 1) { row = v1; col = ml; }
            else if (cD == 2) { row = ml; col = v0; }
            else              { row = ml; col = v1; }
            double r1 = 0.0, r2 = 0.0;
            #pragma unroll
            for (int k = 0; k < 4; ++k) {
                const int la = cA ? (row*4 + k) : (row + 16*k);
                const int lb = cB ? (col*4 + k) : (col + 16*k);
                if (cS == 0) {
                    r1 += (double)(la + 1) * (double)(lb + 65);
                    r2 += (double)(1 + ((la*7+3) % 61)) * (double)(2 + ((lb*13+5) % 53));
                } else {
                    r1 += (double)(lb + 1) * (double)(la + 65);
                    r2 += (double)(1 + ((lb*7+3) % 61)) * (double)(2 + ((la*13+5) % 53));
                }
            }
            if (c1[r] != r1 || c2[r] != r2) ok = false;
        }
        if (__ballot(ok) == ~0ull) best = h;
    }
    if (l == 0) {
        fl[0] = (best >= 0) ? 1.0 : 0.0;
        fl[1] = (double)((best >= 0) ? (best >> 4)      : 0);
        fl[2] = (double)((best >= 0) ? ((best >> 3) & 1) : 0);
        fl[3] = (double)((best >= 0) ? ((best >> 2) & 1) : 0);
        fl[4] = (double)((best >= 0) ? (best & 3)        : 0);
    }
}

// ---------------- fused kernel ----------------
// one block (16 waves) per molecule.  BASE = round-8/10 verified structure
// (75.0/75.7 us).  Change vs round 10 = round 11's double-buffered
// single-factor gram (S = C C^T, C = T*diag(sqrt(w)), ping-pong Cd0/Cd1,
// ONE barrier per chunk) BUT with `#pragma unroll 1` on the chunk loop.
// Round 11's 30-double/thread spill is attributed to full unroll
// software-pipelining the un-fenced loop; unroll 1 fences it.  areg is
// scalarized (areg0..3) because cc is runtime under unroll 1 (rule #20:
// dynamic-indexed register arrays go to scratch).
// k-range tile split kept (round 10, neutral).  Identity 1: out = u.
// Identity 2: sa.t0b = ua.gb, sb.t0b = ub.gb.  Lambda via lam_sh + barrier.
__global__ __launch_bounds__(1024)
void k_fused(const float* __restrict__ pos, const float* __restrict__ T,
             const int* __restrict__ eidx, const float* __restrict__ nattr,
             const float* __restrict__ eneg, const float* __restrict__ qtot,
             const float* __restrict__ hard, const float* __restrict__ covr,
             const int* __restrict__ an, const double* __restrict__ flq,
             float* __restrict__ outp)
{
    const int m = blockIdx.x, tid = threadIdx.x;
    const int jl = tid & 63;        // lane
    const int rg = tid >> 6;        // wave id 0..15
    const int kl = jl >> 4, ml = jl & 15;

    __shared__ double R[2*64*66];   // Cd0,Cd1 | SB,Pm   (67584 B)
    __shared__ double AB[64*65];    // A then M/L        (33280 B)
    __shared__ double w_sl[512];    // w
    __shared__ double rw_sl[512];   // sqrt(w)
    __shared__ double posd[192], sig_s[64], dg_s[64], eneg_s[64];
    __shared__ double t0a_s[64], t0b_s[64], ga_s[64], gb_s[64];
    __shared__ double ua_s[64], ub_s[64];
    __shared__ double dinv_s[64], dvec_s[64];
    __shared__ double lam_sh, sw_sh;

    double* const Cd0 = R;          // [64][66] f64, gram ping buffer
    double* const Cd1 = R + 64*66;  // [64][66] f64, gram pong buffer
    double* const SB = R;           // [64][66] f64, S (post-gram .. end)
    double* const Pm = R + 64*66;   // [64][66] f64, P = A*S

    // probed MFMA layout (k0 ran before us; deterministic)
    const int cS = (int)flq[1], cA = (int)flq[2], cB = (int)flq[3], cD = (int)flq[4];
    const int aRow = cA ? (jl >> 2) : ml;
    const int aK   = cA ? (jl & 3)  : kl;
    const int bRow = cB ? (jl >> 2) : ml;
    const int bK   = cB ? (jl & 3)  : kl;
    int drow[4], dcol[4];
    #pragma unroll
    for (int r = 0; r < 4; ++r) {
        const int v0 = 4*kl + r, v1 = kl + 4*r;
        if (cD == 0)      { drow[r] = v0; dcol[r] = ml; }
        else if (cD == 1) { drow[r] = v1; dcol[r] = ml; }
        else if (cD == 2) { drow[r] = ml; dcol[r] = v0; }
        else              { drow[r] = ml; dcol[r] = v1; }
    }

    const float* Tm = T + (size_t)m*64*512;
    const int srow = tid >> 4, sc4 = (tid & 15) * 4;

    // earliest possible chunk-0 prefetch
    float4 v = *(const float4*)&Tm[srow*512 + sc4];

    // ---- phase A: per-atom loads ----
    if (tid < 64) {
        posd[3*tid+0] = (double)pos[(m*64+tid)*3+0];
        posd[3*tid+1] = (double)pos[(m*64+tid)*3+1];
        posd[3*tid+2] = (double)pos[(m*64+tid)*3+2];
        double r = (double)covr[an[m*64+tid]];
        sig_s[tid] = r*r;
        const float* np_ = nattr + (size_t)(m*64+tid)*10;
        float best = np_[0]; int bi = 0;
        #pragma unroll
        for (int k = 1; k < 10; ++k) { float vv = np_[k]; if (vv > best) { best = vv; bi = k; } }
        dg_s[tid] = (double)hard[bi] + 1.0/(SQRT_PI*r);
    } else if (tid < 128) {
        int ll = tid - 64;
        eneg_s[ll] = (double)eneg[m*64 + ll];
    }
    __syncthreads();

    // ---- phase B: edge weights w, sqrt(w) (tid<512) ----
    if (tid < 512) {
        const int a0 = eidx[(size_t)m*1024 + tid];
        const int a1 = eidx[(size_t)m*1024 + 512 + tid];
        double dx = posd[3*a0+0]-posd[3*a1+0];
        double dy = posd[3*a0+1]-posd[3*a1+1];
        double dz = posd[3*a0+2]-posd[3*a1+2];
        double d  = sqrt(dx*dx+dy*dy+dz*dz);
        double w  = 1.0 / (1.0/cos(PI_OVER_2RC*d) - 1.0);
        w_sl[tid]  = w;
        rw_sl[tid] = sqrt(w);
    }
    __syncthreads();   // rw visible for prologue staging

    // ---- Gram work assignment: 10 tiles, diag waves {0,5,10,15} full-k,
    //      off-diag pairs split by k-range. wm: 0=kk 0..15, 1=kk 0..7, 2=kk 8..15.
    int tp, tq, wm;
    switch (rg) {
        case 0:  tp=0; tq=0; wm=0; break;
        case 5:  tp=1; tq=1; wm=0; break;
        case 10: tp=2; tq=2; wm=0; break;
        case 15: tp=3; tq=3; wm=0; break;
        case 1:  tp=1; tq=0; wm=1; break;
        case 2:  tp=1; tq=0; wm=2; break;
        case 3:  tp=2; tq=0; wm=1; break;
        case 4:  tp=2; tq=0; wm=2; break;
        case 6:  tp=2; tq=1; wm=1; break;
        case 7:  tp=2; tq=1; wm=2; break;
        case 8:  tp=3; tq=0; wm=1; break;
        case 9:  tp=3; tq=0; wm=2; break;
        case 11: tp=3; tq=1; wm=1; break;
        case 12: tp=3; tq=1; wm=2; break;
        case 13: tp=3; tq=2; wm=1; break;
        default: tp=3; tq=2; wm=2; break;   // rg == 14
    }
    const double* ca_b = &Cd0[(size_t)(tp*16 + aRow)*66 + aK];
    const double* cb_b = &Cd0[(size_t)(tq*16 + bRow)*66 + bK];
    dbl4 vacc = {0.0, 0.0, 0.0, 0.0};
    double t0b_p = 0.0;
    double areg0, areg1, areg2, areg3;

    // ---- prologue: stage chunk 0 into Cd0, prefetch chunk 1 ----
    {
        const double r0 = rw_sl[sc4+0], r1 = rw_sl[sc4+1];
        const double r2 = rw_sl[sc4+2], r3 = rw_sl[sc4+3];
        const double c0 = (double)v.x*r0, c1 = (double)v.y*r1;
        const double c2 = (double)v.z*r2, c3 = (double)v.w*r3;
        double2 p0; p0.x = c0; p0.y = c1;
        double2 p1; p1.x = c2; p1.y = c3;
        *(double2*)&Cd0[srow*66 + sc4]     = p0;
        *(double2*)&Cd0[srow*66 + sc4 + 2] = p1;
        t0b_p += c0*r0 + c1*r1 + c2*r2 + c3*r3;
        v = *(const float4*)&Tm[srow*512 + 64 + sc4];
    }
    __syncthreads();   // Cd0 (chunk 0) visible

    #pragma unroll 1
    for (int cc = 0; cc < 8; ++cc) {
        // stage chunk cc+1 into the other buffer (overlaps this chunk's MFMA)
        if (cc < 7) {
            const int e = (cc+1)*64 + sc4;
            const double r0 = rw_sl[e+0], r1 = rw_sl[e+1];
            const double r2 = rw_sl[e+2], r3 = rw_sl[e+3];
            const double c0 = (double)v.x*r0, c1 = (double)v.y*r1;
            const double c2 = (double)v.z*r2, c3 = (double)v.w*r3;
            double* Cw = (((cc+1) & 1) ? Cd1 : Cd0);
            double2 p0; p0.x = c0; p0.y = c1;
            double2 p1; p1.x = c2; p1.y = c3;
            *(double2*)&Cw[srow*66 + sc4]     = p0;
            *(double2*)&Cw[srow*66 + sc4 + 2] = p1;
            t0b_p += c0*r0 + c1*r1 + c2*r2 + c3*r3;
            if (cc < 6) v = *(const float4*)&Tm[srow*512 + (cc+2)*64 + sc4];
        }
        if (cc == 0 && tid >= 128 && tid < 192) {  // wave2: sum(w) (cheap, once)
            const int ll = tid - 128;
            double s = 0.0;
            #pragma unroll
            for (int c = 0; c < 8; ++c) s += w_sl[c*64 + ll];
            #pragma unroll
            for (int off = 32; off > 0; off >>= 1) s += __shfl_down(s, off);
            if (ll == 0) sw_sh = s;
        }
        if (cc < 4) {                              // A-build under MFMA shadow
            const int i = rg + 16*cc;
            double av = a_entry(i, jl, posd, sig_s, dg_s);
            AB[i*65 + jl] = av;
            if (cc == 0)      areg0 = av;
            else if (cc == 1) areg1 = av;
            else if (cc == 2) areg2 = av;
            else              areg3 = av;
        }
        const int bo = (cc & 1) * 4224;            // current buffer offset (elements)
        if (wm == 0) {
            #pragma unroll
            for (int kk = 0; kk < 16; ++kk)
                vacc = mfma64(cS, ca_b[bo + kk*4], cb_b[bo + kk*4], vacc);
        } else if (wm == 1) {
            #pragma unroll
            for (int kk = 0; kk < 8; ++kk)
                vacc = mfma64(cS, ca_b[bo + kk*4], cb_b[bo + kk*4], vacc);
        } else {
            #pragma unroll
            for (int kk = 8; kk < 16; ++kk)
                vacc = mfma64(cS, ca_b[bo + kk*4], cb_b[bo + kk*4], vacc);
        }
        __syncthreads();   // reads of buf[cc&1] done; staged chunk cc+1 visible
    }
    // last loop barrier doubles as the gram->SB transition barrier

    // ---- S assembly: full/first-half writers first, second-half adders second ----
    if (wm != 2) {
        #pragma unroll
        for (int r = 0; r < 4; ++r) {
            const int ri = tp*16 + drow[r], cj = tq*16 + dcol[r];
            SB[ri*66 + cj] = vacc[r];
            if (tp != tq) SB[cj*66 + ri] = vacc[r];
        }
    }
    {   // t0b: reduce 16 column-group partials per row (register-only)
        double t = t0b_p;
        t += __shfl_down(t, 8, 16);
        t += __shfl_down(t, 4, 16);
        t += __shfl_down(t, 2, 16);
        t += __shfl_down(t, 1, 16);
        if ((tid & 15) == 0) t0b_s[tid >> 4] = t;
    }
    __syncthreads();
    if (wm == 2) {
        #pragma unroll
        for (int r = 0; r < 4; ++r) {
            const int ri = tp*16 + drow[r], cj = tq*16 + dcol[r];
            const double vv = vacc[r];
            SB[ri*66 + cj] += vv;
            if (tp != tq) SB[cj*66 + ri] += vv;
        }
    }
    __syncthreads();   // S complete

    // ---- t0a = -S·eneg (LDS-S, 16-lane reduce) ----
    {
        const int c16 = tid & 15, row16 = tid >> 4;
        double a = 0.0;
        #pragma unroll
        for (int kk = 0; kk < 4; ++kk)
            a += SB[row16*66 + 4*c16 + kk] * eneg_s[4*c16 + kk];
        a += __shfl_down(a, 8, 16);
        a += __shfl_down(a, 4, 16);
        a += __shfl_down(a, 2, 16);
        a += __shfl_down(a, 1, 16);
        if (c16 == 0) t0a_s[row16] = -a;
    }
    __syncthreads();

    // ---- g = A·t0 via areg wave reduction (scalarized areg) ----
    {
        const double ta = t0a_s[jl], tb = t0b_s[jl];
        double ra0 = areg0*ta, ra1 = areg1*ta, ra2 = areg2*ta, ra3 = areg3*ta;
        double rb0 = areg0*tb, rb1 = areg1*tb, rb2 = areg2*tb, rb3 = areg3*tb;
        #pragma unroll
        for (int off = 32; off > 0; off >>= 1) {
            ra0 += __shfl_down(ra0, off); ra1 += __shfl_down(ra1, off);
            ra2 += __shfl_down(ra2, off); ra3 += __shfl_down(ra3, off);
            rb0 += __shfl_down(rb0, off); rb1 += __shfl_down(rb1, off);
            rb2 += __shfl_down(rb2, off); rb3 += __shfl_down(rb3, off);
        }
        if (jl == 0) {
            ga_s[rg+ 0] = ra0; ga_s[rg+16] = ra1; ga_s[rg+32] = ra2; ga_s[rg+48] = ra3;
            gb_s[rg+ 0] = rb0; gb_s[rg+16] = rb1; gb_s[rg+32] = rb2; gb_s[rg+48] = rb3;
        }
    }
    __syncthreads();

    // ---- GEMM1: P = A·S (16 tiles / 16 waves, immediate-offset operands) ----
    const int ti = rg >> 2, tj = rg & 3;
    {
        const double* xb = &AB[(size_t)(ti*16 + aRow)*65 + aK];
        const double* yb = &SB[(size_t)bK*66 + tj*16 + bRow];
        dbl4 pacc = {0.0, 0.0, 0.0, 0.0};
        #pragma unroll
        for (int kk = 0; kk < 16; ++kk)
            pacc = mfma64(cS, xb[kk*4], yb[kk*264], pacc);
        #pragma unroll
        for (int r = 0; r < 4; ++r)
            Pm[(ti*16 + drow[r])*66 + tj*16 + dcol[r]] = pacc[r];   // Pm != SB, no barrier needed
    }
    __syncthreads();   // P visible

    // ---- GEMM2: M = A + P·A, overwrite AB ----
    {
        dbl4 macc;
        #pragma unroll
        for (int r = 0; r < 4; ++r)
            macc[r] = AB[(ti*16 + drow[r])*65 + tj*16 + dcol[r]];
        const double* xb = &Pm[(size_t)(ti*16 + aRow)*66 + aK];
        const double* yb = &AB[(size_t)bK*65 + tj*16 + bRow];
        #pragma unroll
        for (int kk = 0; kk < 16; ++kk)
            macc = mfma64(cS, xb[kk*4], yb[kk*260], macc);
        __syncthreads();   // all GEMM2 AB reads done
        #pragma unroll
        for (int r = 0; r < 4; ++r)
            AB[(ti*16 + drow[r])*65 + tj*16 + dcol[r]] = macc[r];
    }
    __syncthreads();

    // ---- blocked LDL^T: wave0 panel factor + trailing updates (verified) ----
    for (int pb = 0; pb < 4; ++pb) {
        const int kb = pb*16;
        if (tid < 64) {
            const int i = tid;
            double pr[16];
            #pragma unroll
            for (int c = 0; c < 16; ++c) pr[c] = AB[i*65 + kb + c];
            #pragma unroll
            for (int c = 0; c < 16; ++c) {
                const int k = kb + c;
                const double Dk = bcast64(pr[c], k);
                const double di = 1.0 / Dk;
                if (i == k) { dinv_s[k] = di; dvec_s[k] = Dk; }
                const double lik = pr[c] * di;
                #pragma unroll
                for (int j = c+1; j < 16; ++j) {
                    const double mkj = bcast64(pr[j], k);
                    if (i > k) pr[j] -= lik * mkj;
                }
                if (i > k) pr[c] = lik;
            }
            #pragma unroll
            for (int c = 0; c < 16; ++c) AB[i*65 + kb + c] = pr[c];
        }
        __syncthreads();
        const int lim = kb + 16;
        if (lim < 64) {
            double tacc[4] = {0.0, 0.0, 0.0, 0.0};
            #pragma unroll 4
            for (int c = 0; c < 16; ++c) {
                double lbv = AB[jl*65 + kb + c] * dvec_s[kb + c];
                #pragma unroll
                for (int p = 0; p < 4; ++p)
                    tacc[p] += AB[(rg+16*p)*65 + kb + c] * lbv;
            }
            if (jl >= lim) {
                #pragma unroll
                for (int p = 0; p < 4; ++p) {
                    int i = rg + 16*p;
                    if (i >= lim) AB[i*65 + jl] -= tacc[p];
                }
            }
        }
        __syncthreads();
    }

    // ---- solves: wave0 does RHS a, wave1 does RHS b (independent chains) ----
    if (tid < 128) {
        const int i = jl;
        double h = (rg == 0) ? ga_s[i] : gb_s[i];
        #pragma unroll
        for (int j = 0; j < 63; ++j) {
            double x = bcast64(h, j);
            double lij = (i > j) ? AB[i*65+j] : 0.0;
            h -= lij*x;
        }
        h *= dinv_s[i];
        #pragma unroll
        for (int j = 63; j > 0; --j) {
            double x = bcast64(h, j);
            double lji = (i < j) ? AB[j*65+i] : 0.0;
            h -= lji*x;
        }
        if (rg == 0) ua_s[i] = h; else ub_s[i] = h;
    }
    __syncthreads();

    // ---- lambda (identities: sa.t0b = ua.gb, sb.t0b = ub.gb), via lam_sh ----
    if (tid < 64) {
        const double ua = ua_s[tid], ub = ub_s[tid], gbv = gb_s[tid];
        double d1 = eneg_s[tid]*t0b_s[tid] + ua*gbv;   // = (eneg + sa)·t0b termwise
        double d2 = ub*gbv;                            // = sb·t0b termwise
        #pragma unroll
        for (int off = 32; off > 0; off >>= 1) {
            d1 += __shfl_down(d1, off);
            d2 += __shfl_down(d2, off);
        }
        if (tid == 0) {
            double sY = -d1;
            double sZ = sw_sh - d2;
            lam_sh = ((double)qtot[m] - sY) / (1.0 - sZ);
        }
    }
    __syncthreads();
    if (tid < 64)
        outp[m*64 + tid] = (float)(ua_s[tid] - lam_sh*ub_s[tid]);
}

extern "C" void kernel_launch(void* const* d_in, const int* in_sizes, int n_in,
                              void* d_out, int out_size, void* d_ws, size_t ws_size,
                              hipStream_t stream) {
    const float* pos  = (const float*)d_in[0];
    const float* T    = (const float*)d_in[1];
    const float* eneg = (const float*)d_in[2];
    const float* nat  = (const float*)d_in[3];
    const float* qt   = (const float*)d_in[4];
    // d_in[5] 'p' unused
    const float* hard = (const float*)d_in[6];
    const float* covr = (const float*)d_in[7];
    const int*   an   = (const int*)d_in[8];
    const int*   eidx = (const int*)d_in[9];
    float* outp = (float*)d_out;
    (void)n_in; (void)out_size; (void)ws_size;

    const int B = in_sizes[4];
    double* ws = (double*)d_ws;   // 5 doubles (probe flags)

    k0_probe<<<dim3(1), dim3(64), 0, stream>>>(ws);
    k_fused<<<dim3(B), dim3(1024), 0, stream>>>(pos, T, eidx, nat, eneg, qt,
                                                hard, covr, an, ws, outp);
}

// Round 13
// 155.513 us; speedup vs baseline: 1.1201x; 1.0122x over previous
//
#include <hip/hip_runtime.h>
#include <math.h>

// Problem constants: B molecules, N=64 atoms, E=512 edges, R_CUT=10
#define SQRT_PI 1.7724538509055160273
#define SQRT_2  1.4142135623730950488
#define PI_OVER_2RC 0.15707963267948966

typedef double dbl4 __attribute__((ext_vector_type(4)));

// ws layout (doubles): flags fl[0..4] only.

__device__ __forceinline__ double bcast64(double v, int lane) {
    union { double d; unsigned int u[2]; } a, r;
    a.d = v;
    r.u[0] = __builtin_amdgcn_readlane(a.u[0], lane);
    r.u[1] = __builtin_amdgcn_readlane(a.u[1], lane);
    return r.d;
}

__device__ __forceinline__ double a_entry(int i, int j, const double* posd,
                                          const double* sig, const double* dg) {
    if (i == j) return dg[i];
    double dx = posd[3*i+0]-posd[3*j+0];
    double dy = posd[3*i+1]-posd[3*j+1];
    double dz = posd[3*i+2]-posd[3*j+2];
    double d  = sqrt(dx*dx+dy*dy+dz*dz);
    double g  = sqrt(sig[i]+sig[j]);
    return erf(d/(SQRT_2*g))/d;
}

// swap-aware MFMA: xv = A-side value, yv = B-side value
__device__ __forceinline__ dbl4 mfma64(int cS, double xv, double yv, dbl4 acc) {
    return cS ? __builtin_amdgcn_mfma_f64_16x16x4f64(yv, xv, acc, 0, 0, 0)
              : __builtin_amdgcn_mfma_f64_16x16x4f64(xv, yv, acc, 0, 0, 0);
}

// ---------------- K0: f64-MFMA layout probe (injective, dual value-set) ----------------
__global__ __launch_bounds__(64)
void k0_probe(double* __restrict__ fl)
{
    const int l = threadIdx.x;
    const int kl = l >> 4, ml = l & 15;
    const double af1 = (double)(l + 1),  bf1 = (double)(l + 65);
    const double af2 = (double)(1 + ((l*7 + 3) % 61));
    const double bf2 = (double)(2 + ((l*13 + 5) % 53));
    dbl4 c1 = {0.0,0.0,0.0,0.0}, c2 = {0.0,0.0,0.0,0.0};
    c1 = __builtin_amdgcn_mfma_f64_16x16x4f64(af1, bf1, c1, 0, 0, 0);
    c2 = __builtin_amdgcn_mfma_f64_16x16x4f64(af2, bf2, c2, 0, 0, 0);
    int best = -1;
    for (int h = 0; h < 32; ++h) {
        if (best >= 0) break;
        const int cS = h >> 4, cA = (h >> 3) & 1, cB = (h >> 2) & 1, cD = h & 3;
        bool ok = true;
        #pragma unroll
        for (int r = 0; r < 4; ++r) {
            int row, col;
            const int v0 = 4*kl + r, v1 = kl + 4*r;
            if (cD == 0)      { row = v0; col = ml; }
            else if (cD == 1) { row = v1; col = ml; }
            else if (cD == 2) { row = ml; col = v0; }
            else              { row = ml; col = v1; }
            double r1 = 0.0, r2 = 0.0;
            #pragma unroll
            for (int k = 0; k < 4; ++k) {
                const int la = cA ? (row*4 + k) : (row + 16*k);
                const int lb = cB ? (col*4 + k) : (col + 16*k);
                if (cS == 0) {
                    r1 += (double)(la + 1) * (double)(lb + 65);
                    r2 += (double)(1 + ((la*7+3) % 61)) * (double)(2 + ((lb*13+5) % 53));
                } else {
                    r1 += (double)(lb + 1) * (double)(la + 65);
                    r2 += (double)(1 + ((lb*7+3) % 61)) * (double)(2 + ((la*13+5) % 53));
                }
            }
            if (c1[r] != r1 || c2[r] != r2) ok = false;
        }
        if (__ballot(ok) == ~0ull) best = h;
    }
    if (l == 0) {
        fl[0] = (best >= 0) ? 1.0 : 0.0;
        fl[1] = (double)((best >= 0) ? (best >> 4)      : 0);
        fl[2] = (double)((best >= 0) ? ((best >> 3) & 1) : 0);
        fl[3] = (double)((best >= 0) ? ((best >> 2) & 1) : 0);
        fl[4] = (double)((best >= 0) ? (best & 3)        : 0);
    }
}

// ---------------- fused kernel ----------------
// one block (16 waves) per molecule.  BASE = round-12 verified structure
// (73.5 us): double-buffered single-factor gram (S = C C^T, C = T*sqrt(w),
// ping-pong Cd0/Cd1, one barrier/chunk, `#pragma unroll 1` fences the
// pipeliner -> no spill), k-range tile split, parallel two-RHS solves,
// lambda identities.  ONE change vs round 12:
//   Symmetric A-build: lower triangle only (2080 entries ~= 2/thread,
//   linear triangle index t -> (i,j) via sqrt + integer fix-up), each
//   thread writes both mirror slots.  Halves the erf VALU work at wave
//   granularity (a masked-lane `if (i<=j)` would save nothing).  areg is
//   no longer tracked through gram; the g-phase re-reads its 4 A-values
//   from LDS (4 ds_read_b64, after existing barriers).
// Identity 1: out = u; Identity 2: sa.t0b = ua.gb, sb.t0b = ub.gb.
// Lambda via lam_sh + barrier (in-register bcast of conditionally-assigned
// value miscompiled in round 5).
__global__ __launch_bounds__(1024)
void k_fused(const float* __restrict__ pos, const float* __restrict__ T,
             const int* __restrict__ eidx, const float* __restrict__ nattr,
             const float* __restrict__ eneg, const float* __restrict__ qtot,
             const float* __restrict__ hard, const float* __restrict__ covr,
             const int* __restrict__ an, const double* __restrict__ flq,
             float* __restrict__ outp)
{
    const int m = blockIdx.x, tid = threadIdx.x;
    const int jl = tid & 63;        // lane
    const int rg = tid >> 6;        // wave id 0..15
    const int kl = jl >> 4, ml = jl & 15;

    __shared__ double R[2*64*66];   // Cd0,Cd1 | SB,Pm   (67584 B)
    __shared__ double AB[64*65];    // A then M/L        (33280 B)
    __shared__ double w_sl[512];    // w
    __shared__ double rw_sl[512];   // sqrt(w)
    __shared__ double posd[192], sig_s[64], dg_s[64], eneg_s[64];
    __shared__ double t0a_s[64], t0b_s[64], ga_s[64], gb_s[64];
    __shared__ double ua_s[64], ub_s[64];
    __shared__ double dinv_s[64], dvec_s[64];
    __shared__ double lam_sh, sw_sh;

    double* const Cd0 = R;          // [64][66] f64, gram ping buffer
    double* const Cd1 = R + 64*66;  // [64][66] f64, gram pong buffer
    double* const SB = R;           // [64][66] f64, S (post-gram .. end)
    double* const Pm = R + 64*66;   // [64][66] f64, P = A*S

    // probed MFMA layout (k0 ran before us; deterministic)
    const int cS = (int)flq[1], cA = (int)flq[2], cB = (int)flq[3], cD = (int)flq[4];
    const int aRow = cA ? (jl >> 2) : ml;
    const int aK   = cA ? (jl & 3)  : kl;
    const int bRow = cB ? (jl >> 2) : ml;
    const int bK   = cB ? (jl & 3)  : kl;
    int drow[4], dcol[4];
    #pragma unroll
    for (int r = 0; r < 4; ++r) {
        const int v0 = 4*kl + r, v1 = kl + 4*r;
        if (cD == 0)      { drow[r] = v0; dcol[r] = ml; }
        else if (cD == 1) { drow[r] = v1; dcol[r] = ml; }
        else if (cD == 2) { drow[r] = ml; dcol[r] = v0; }
        else              { drow[r] = ml; dcol[r] = v1; }
    }

    const float* Tm = T + (size_t)m*64*512;
    const int srow = tid >> 4, sc4 = (tid & 15) * 4;

    // earliest possible chunk-0 prefetch
    float4 v = *(const float4*)&Tm[srow*512 + sc4];

    // ---- phase A: per-atom loads ----
    if (tid < 64) {
        posd[3*tid+0] = (double)pos[(m*64+tid)*3+0];
        posd[3*tid+1] = (double)pos[(m*64+tid)*3+1];
        posd[3*tid+2] = (double)pos[(m*64+tid)*3+2];
        double r = (double)covr[an[m*64+tid]];
        sig_s[tid] = r*r;
        const float* np_ = nattr + (size_t)(m*64+tid)*10;
        float best = np_[0]; int bi = 0;
        #pragma unroll
        for (int k = 1; k < 10; ++k) { float vv = np_[k]; if (vv > best) { best = vv; bi = k; } }
        dg_s[tid] = (double)hard[bi] + 1.0/(SQRT_PI*r);
    } else if (tid < 128) {
        int ll = tid - 64;
        eneg_s[ll] = (double)eneg[m*64 + ll];
    }
    __syncthreads();

    // ---- phase B: edge weights w, sqrt(w) (tid<512) ----
    if (tid < 512) {
        const int a0 = eidx[(size_t)m*1024 + tid];
        const int a1 = eidx[(size_t)m*1024 + 512 + tid];
        double dx = posd[3*a0+0]-posd[3*a1+0];
        double dy = posd[3*a0+1]-posd[3*a1+1];
        double dz = posd[3*a0+2]-posd[3*a1+2];
        double d  = sqrt(dx*dx+dy*dy+dz*dz);
        double w  = 1.0 / (1.0/cos(PI_OVER_2RC*d) - 1.0);
        w_sl[tid]  = w;
        rw_sl[tid] = sqrt(w);
    }
    __syncthreads();   // rw visible for prologue staging

    // ---- Gram work assignment: 10 tiles, diag waves {0,5,10,15} full-k,
    //      off-diag pairs split by k-range. wm: 0=kk 0..15, 1=kk 0..7, 2=kk 8..15.
    int tp, tq, wm;
    switch (rg) {
        case 0:  tp=0; tq=0; wm=0; break;
        case 5:  tp=1; tq=1; wm=0; break;
        case 10: tp=2; tq=2; wm=0; break;
        case 15: tp=3; tq=3; wm=0; break;
        case 1:  tp=1; tq=0; wm=1; break;
        case 2:  tp=1; tq=0; wm=2; break;
        case 3:  tp=2; tq=0; wm=1; break;
        case 4:  tp=2; tq=0; wm=2; break;
        case 6:  tp=2; tq=1; wm=1; break;
        case 7:  tp=2; tq=1; wm=2; break;
        case 8:  tp=3; tq=0; wm=1; break;
        case 9:  tp=3; tq=0; wm=2; break;
        case 11: tp=3; tq=1; wm=1; break;
        case 12: tp=3; tq=1; wm=2; break;
        case 13: tp=3; tq=2; wm=1; break;
        default: tp=3; tq=2; wm=2; break;   // rg == 14
    }
    const double* ca_b = &Cd0[(size_t)(tp*16 + aRow)*66 + aK];
    const double* cb_b = &Cd0[(size_t)(tq*16 + bRow)*66 + bK];
    dbl4 vacc = {0.0, 0.0, 0.0, 0.0};
    double t0b_p = 0.0;

    // ---- prologue: stage chunk 0 into Cd0, prefetch chunk 1 ----
    {
        const double r0 = rw_sl[sc4+0], r1 = rw_sl[sc4+1];
        const double r2 = rw_sl[sc4+2], r3 = rw_sl[sc4+3];
        const double c0 = (double)v.x*r0, c1 = (double)v.y*r1;
        const double c2 = (double)v.z*r2, c3 = (double)v.w*r3;
        double2 p0; p0.x = c0; p0.y = c1;
        double2 p1; p1.x = c2; p1.y = c3;
        *(double2*)&Cd0[srow*66 + sc4]     = p0;
        *(double2*)&Cd0[srow*66 + sc4 + 2] = p1;
        t0b_p += c0*r0 + c1*r1 + c2*r2 + c3*r3;
        v = *(const float4*)&Tm[srow*512 + 64 + sc4];
    }
    __syncthreads();   // Cd0 (chunk 0) visible

    #pragma unroll 1
    for (int cc = 0; cc < 8; ++cc) {
        // stage chunk cc+1 into the other buffer (overlaps this chunk's MFMA)
        if (cc < 7) {
            const int e = (cc+1)*64 + sc4;
            const double r0 = rw_sl[e+0], r1 = rw_sl[e+1];
            const double r2 = rw_sl[e+2], r3 = rw_sl[e+3];
            const double c0 = (double)v.x*r0, c1 = (double)v.y*r1;
            const double c2 = (double)v.z*r2, c3 = (double)v.w*r3;
            double* Cw = (((cc+1) & 1) ? Cd1 : Cd0);
            double2 p0; p0.x = c0; p0.y = c1;
            double2 p1; p1.x = c2; p1.y = c3;
            *(double2*)&Cw[srow*66 + sc4]     = p0;
            *(double2*)&Cw[srow*66 + sc4 + 2] = p1;
            t0b_p += c0*r0 + c1*r1 + c2*r2 + c3*r3;
            if (cc < 6) v = *(const float4*)&Tm[srow*512 + (cc+2)*64 + sc4];
        }
        if (cc == 0 && tid >= 128 && tid < 192) {  // wave2: sum(w) (cheap, once)
            const int ll = tid - 128;
            double s = 0.0;
            #pragma unroll
            for (int c = 0; c < 8; ++c) s += w_sl[c*64 + ll];
            #pragma unroll
            for (int off = 32; off > 0; off >>= 1) s += __shfl_down(s, off);
            if (ll == 0) sw_sh = s;
        }
        // ---- symmetric A-build under MFMA shadow: lower triangle only,
        //      linear index t -> (i,j), mirror-write.  2080 entries total:
        //      cc0: t=tid, cc1: t=tid+1024, cc2: t=tid+2048 (tid<32).
        if (cc < 3) {
            int t = -1;
            if (cc == 0) t = tid;
            else if (cc == 1) t = tid + 1024;
            else if (tid < 32) t = tid + 2048;
            if (t >= 0) {
                int i = (int)((sqrt(8.0*(double)t + 1.0) - 1.0) * 0.5);
                if ((i+1)*(i+2)/2 <= t) ++i;     // fix sqrt rounding
                if (i*(i+1)/2 > t) --i;
                const int j = t - i*(i+1)/2;     // j <= i
                double av = a_entry(i, j, posd, sig_s, dg_s);
                AB[i*65 + j] = av;
                AB[j*65 + i] = av;
            }
        }
        const int bo = (cc & 1) * 4224;            // current buffer offset (elements)
        if (wm == 0) {
            #pragma unroll
            for (int kk = 0; kk < 16; ++kk)
                vacc = mfma64(cS, ca_b[bo + kk*4], cb_b[bo + kk*4], vacc);
        } else if (wm == 1) {
            #pragma unroll
            for (int kk = 0; kk < 8; ++kk)
                vacc = mfma64(cS, ca_b[bo + kk*4], cb_b[bo + kk*4], vacc);
        } else {
            #pragma unroll
            for (int kk = 8; kk < 16; ++kk)
                vacc = mfma64(cS, ca_b[bo + kk*4], cb_b[bo + kk*4], vacc);
        }
        __syncthreads();   // reads of buf[cc&1] done; staged chunk cc+1 visible
    }
    // last loop barrier doubles as the gram->SB transition barrier

    // ---- S assembly: full/first-half writers first, second-half adders second ----
    if (wm != 2) {
        #pragma unroll
        for (int r = 0; r < 4; ++r) {
            const int ri = tp*16 + drow[r], cj = tq*16 + dcol[r];
            SB[ri*66 + cj] = vacc[r];
            if (tp != tq) SB[cj*66 + ri] = vacc[r];
        }
    }
    {   // t0b: reduce 16 column-group partials per row (register-only)
        double t = t0b_p;
        t += __shfl_down(t, 8, 16);
        t += __shfl_down(t, 4, 16);
        t += __shfl_down(t, 2, 16);
        t += __shfl_down(t, 1, 16);
        if ((tid & 15) == 0) t0b_s[tid >> 4] = t;
    }
    __syncthreads();
    if (wm == 2) {
        #pragma unroll
        for (int r = 0; r < 4; ++r) {
            const int ri = tp*16 + drow[r], cj = tq*16 + dcol[r];
            const double vv = vacc[r];
            SB[ri*66 + cj] += vv;
            if (tp != tq) SB[cj*66 + ri] += vv;
        }
    }
    __syncthreads();   // S complete

    // ---- t0a = -S·eneg (LDS-S, 16-lane reduce) ----
    {
        const int c16 = tid & 15, row16 = tid >> 4;
        double a = 0.0;
        #pragma unroll
        for (int kk = 0; kk < 4; ++kk)
            a += SB[row16*66 + 4*c16 + kk] * eneg_s[4*c16 + kk];
        a += __shfl_down(a, 8, 16);
        a += __shfl_down(a, 4, 16);
        a += __shfl_down(a, 2, 16);
        a += __shfl_down(a, 1, 16);
        if (c16 == 0) t0a_s[row16] = -a;
    }
    __syncthreads();

    // ---- g = A·t0 via wave reduction (A-column read back from LDS) ----
    {
        const double areg0 = AB[(rg+ 0)*65 + jl];
        const double areg1 = AB[(rg+16)*65 + jl];
        const double areg2 = AB[(rg+32)*65 + jl];
        const double areg3 = AB[(rg+48)*65 + jl];
        const double ta = t0a_s[jl], tb = t0b_s[jl];
        double ra0 = areg0*ta, ra1 = areg1*ta, ra2 = areg2*ta, ra3 = areg3*ta;
        double rb0 = areg0*tb, rb1 = areg1*tb, rb2 = areg2*tb, rb3 = areg3*tb;
        #pragma unroll
        for (int off = 32; off > 0; off >>= 1) {
            ra0 += __shfl_down(ra0, off); ra1 += __shfl_down(ra1, off);
            ra2 += __shfl_down(ra2, off); ra3 += __shfl_down(ra3, off);
            rb0 += __shfl_down(rb0, off); rb1 += __shfl_down(rb1, off);
            rb2 += __shfl_down(rb2, off); rb3 += __shfl_down(rb3, off);
        }
        if (jl == 0) {
            ga_s[rg+ 0] = ra0; ga_s[rg+16] = ra1; ga_s[rg+32] = ra2; ga_s[rg+48] = ra3;
            gb_s[rg+ 0] = rb0; gb_s[rg+16] = rb1; gb_s[rg+32] = rb2; gb_s[rg+48] = rb3;
        }
    }
    __syncthreads();

    // ---- GEMM1: P = A·S (16 tiles / 16 waves, immediate-offset operands) ----
    const int ti = rg >> 2, tj = rg & 3;
    {
        const double* xb = &AB[(size_t)(ti*16 + aRow)*65 + aK];
        const double* yb = &SB[(size_t)bK*66 + tj*16 + bRow];
        dbl4 pacc = {0.0, 0.0, 0.0, 0.0};
        #pragma unroll
        for (int kk = 0; kk < 16; ++kk)
            pacc = mfma64(cS, xb[kk*4], yb[kk*264], pacc);
        #pragma unroll
        for (int r = 0; r < 4; ++r)
            Pm[(ti*16 + drow[r])*66 + tj*16 + dcol[r]] = pacc[r];   // Pm != SB, no barrier needed
    }
    __syncthreads();   // P visible

    // ---- GEMM2: M = A + P·A, overwrite AB ----
    {
        dbl4 macc;
        #pragma unroll
        for (int r = 0; r < 4; ++r)
            macc[r] = AB[(ti*16 + drow[r])*65 + tj*16 + dcol[r]];
        const double* xb = &Pm[(size_t)(ti*16 + aRow)*66 + aK];
        const double* yb = &AB[(size_t)bK*65 + tj*16 + bRow];
        #pragma unroll
        for (int kk = 0; kk < 16; ++kk)
            macc = mfma64(cS, xb[kk*4], yb[kk*260], macc);
        __syncthreads();   // all GEMM2 AB reads done
        #pragma unroll
        for (int r = 0; r < 4; ++r)
            AB[(ti*16 + drow[r])*65 + tj*16 + dcol[r]] = macc[r];
    }
    __syncthreads();

    // ---- blocked LDL^T: wave0 panel factor + trailing updates (verified) ----
    for (int pb = 0; pb < 4; ++pb) {
        const int kb = pb*16;
        if (tid < 64) {
            const int i = tid;
            double pr[16];
            #pragma unroll
            for (int c = 0; c < 16; ++c) pr[c] = AB[i*65 + kb + c];
            #pragma unroll
            for (int c = 0; c < 16; ++c) {
                const int k = kb + c;
                const double Dk = bcast64(pr[c], k);
                const double di = 1.0 / Dk;
                if (i == k) { dinv_s[k] = di; dvec_s[k] = Dk; }
                const double lik = pr[c] * di;
                #pragma unroll
                for (int j = c+1; j < 16; ++j) {
                    const double mkj = bcast64(pr[j], k);
                    if (i > k) pr[j] -= lik * mkj;
                }
                if (i > k) pr[c] = lik;
            }
            #pragma unroll
            for (int c = 0; c < 16; ++c) AB[i*65 + kb + c] = pr[c];
        }
        __syncthreads();
        const int lim = kb + 16;
        if (lim < 64) {
            double tacc[4] = {0.0, 0.0, 0.0, 0.0};
            #pragma unroll 4
            for (int c = 0; c < 16; ++c) {
                double lbv = AB[jl*65 + kb + c] * dvec_s[kb + c];
                #pragma unroll
                for (int p = 0; p < 4; ++p)
                    tacc[p] += AB[(rg+16*p)*65 + kb + c] * lbv;
            }
            if (jl >= lim) {
                #pragma unroll
                for (int p = 0; p < 4; ++p) {
                    int i = rg + 16*p;
                    if (i >= lim) AB[i*65 + jl] -= tacc[p];
                }
            }
        }
        __syncthreads();
    }

    // ---- solves: wave0 does RHS a, wave1 does RHS b (independent chains) ----
    if (tid < 128) {
        const int i = jl;
        double h = (rg == 0) ? ga_s[i] : gb_s[i];
        #pragma unroll
        for (int j = 0; j < 63; ++j) {
            double x = bcast64(h, j);
            double lij = (i > j) ? AB[i*65+j] : 0.0;
            h -= lij*x;
        }
        h *= dinv_s[i];
        #pragma unroll
        for (int j = 63; j > 0; --j) {
            double x = bcast64(h, j);
            double lji = (i < j) ? AB[j*65+i] : 0.0;
            h -= lji*x;
        }
        if (rg == 0) ua_s[i] = h; else ub_s[i] = h;
    }
    __syncthreads();

    // ---- lambda (identities: sa.t0b = ua.gb, sb.t0b = ub.gb), via lam_sh ----
    if (tid < 64) {
        const double ua = ua_s[tid], ub = ub_s[tid], gbv = gb_s[tid];
        double d1 = eneg_s[tid]*t0b_s[tid] + ua*gbv;   // = (eneg + sa)·t0b termwise
        double d2 = ub*gbv;                            // = sb·t0b termwise
        #pragma unroll
        for (int off = 32; off > 0; off >>= 1) {
            d1 += __shfl_down(d1, off);
            d2 += __shfl_down(d2, off);
        }
        if (tid == 0) {
            double sY = -d1;
            double sZ = sw_sh - d2;
            lam_sh = ((double)qtot[m] - sY) / (1.0 - sZ);
        }
    }
    __syncthreads();
    if (tid < 64)
        outp[m*64 + tid] = (float)(ua_s[tid] - lam_sh*ub_s[tid]);
}

extern "C" void kernel_launch(void* const* d_in, const int* in_sizes, int n_in,
                              void* d_out, int out_size, void* d_ws, size_t ws_size,
                              hipStream_t stream) {
    const float* pos  = (const float*)d_in[0];
    const float* T    = (const float*)d_in[1];
    const float* eneg = (const float*)d_in[2];
    const float* nat  = (const float*)d_in[3];
    const float* qt   = (const float*)d_in[4];
    // d_in[5] 'p' unused
    const float* hard = (const float*)d_in[6];
    const float* covr = (const float*)d_in[7];
    const int*   an   = (const int*)d_in[8];
    const int*   eidx = (const int*)d_in[9];
    float* outp = (float*)d_out;
    (void)n_in; (void)out_size; (void)ws_size;

    const int B = in_sizes[4];
    double* ws = (double*)d_ws;   // 5 doubles (probe flags)

    k0_probe<<<dim3(1), dim3(64), 0, stream>>>(ws);
    k_fused<<<dim3(B), dim3(1024), 0, stream>>>(pos, T, eidx, nat, eneg, qt,
                                                hard, covr, an, ws, outp);
}

// Round 14
// 153.394 us; speedup vs baseline: 1.1355x; 1.0138x over previous
//
#include <hip/hip_runtime.h>
#include <math.h>

// Problem constants: B molecules, N=64 atoms, E=512 edges, R_CUT=10
#define SQRT_PI 1.7724538509055160273
#define SQRT_2  1.4142135623730950488
#define PI_OVER_2RC 0.15707963267948966

typedef double dbl4 __attribute__((ext_vector_type(4)));

__device__ __forceinline__ double bcast64(double v, int lane) {
    union { double d; unsigned int u[2]; } a, r;
    a.d = v;
    r.u[0] = __builtin_amdgcn_readlane(a.u[0], lane);
    r.u[1] = __builtin_amdgcn_readlane(a.u[1], lane);
    return r.d;
}

__device__ __forceinline__ double a_entry(int i, int j, const double* posd,
                                          const double* sig, const double* dg) {
    if (i == j) return dg[i];
    double dx = posd[3*i+0]-posd[3*j+0];
    double dy = posd[3*i+1]-posd[3*j+1];
    double dz = posd[3*i+2]-posd[3*j+2];
    double d  = sqrt(dx*dx+dy*dy+dz*dz);
    double g  = sqrt(sig[i]+sig[j]);
    return erf(d/(SQRT_2*g))/d;
}

// swap-aware MFMA: xv = A-side value, yv = B-side value
__device__ __forceinline__ dbl4 mfma64(int cS, double xv, double yv, dbl4 acc) {
    return cS ? __builtin_amdgcn_mfma_f64_16x16x4f64(yv, xv, acc, 0, 0, 0)
              : __builtin_amdgcn_mfma_f64_16x16x4f64(xv, yv, acc, 0, 0, 0);
}

// ---------------- fused kernel (SINGLE dispatch) ----------------
// one block (16 waves) per molecule.  BASE = round-13 verified structure
// (71.8 us): double-buffered single-factor gram (S = C C^T, C = T*sqrt(w),
// ping-pong Cd0/Cd1, one barrier/chunk, `#pragma unroll 1` fences the
// pipeliner -> no spill), k-range tile split, symmetric lower-triangle
// A-build (mirror-write), parallel two-RHS solves, lambda identities.
// ONE change vs round 13:
//   Inline MFMA-layout probe in the preamble (waves 0-3, 8 hypotheses each,
//   per-wave LDS result slot, max-combine) -- k0_probe kernel + its launch
//   deleted; per-atom loads moved to waves 4-6 (round-3-verified pattern).
// Identity 1: out = u; Identity 2: sa.t0b = ua.gb, sb.t0b = ub.gb.
// Lambda via lam_sh + barrier (in-register bcast of conditionally-assigned
// value miscompiled in round 5).
__global__ __launch_bounds__(1024)
void k_fused(const float* __restrict__ pos, const float* __restrict__ T,
             const int* __restrict__ eidx, const float* __restrict__ nattr,
             const float* __restrict__ eneg, const float* __restrict__ qtot,
             const float* __restrict__ hard, const float* __restrict__ covr,
             const int* __restrict__ an, float* __restrict__ outp)
{
    const int m = blockIdx.x, tid = threadIdx.x;
    const int jl = tid & 63;        // lane
    const int rg = tid >> 6;        // wave id 0..15
    const int kl = jl >> 4, ml = jl & 15;

    __shared__ double R[2*64*66];   // Cd0,Cd1 | SB,Pm   (67584 B)
    __shared__ double AB[64*65];    // A then M/L        (33280 B)
    __shared__ double w_sl[512];    // w
    __shared__ double rw_sl[512];   // sqrt(w)
    __shared__ double posd[192], sig_s[64], dg_s[64], eneg_s[64];
    __shared__ double t0a_s[64], t0b_s[64], ga_s[64], gb_s[64];
    __shared__ double ua_s[64], ub_s[64];
    __shared__ double dinv_s[64], dvec_s[64];
    __shared__ double lam_sh, sw_sh;
    __shared__ int fl_w[4];

    double* const Cd0 = R;          // [64][66] f64, gram ping buffer
    double* const Cd1 = R + 64*66;  // [64][66] f64, gram pong buffer
    double* const SB = R;           // [64][66] f64, S (post-gram .. end)
    double* const Pm = R + 64*66;   // [64][66] f64, P = A*S

    const float* Tm = T + (size_t)m*64*512;
    const int srow = tid >> 4, sc4 = (tid & 15) * 4;

    // earliest possible chunk-0 prefetch
    float4 v = *(const float4*)&Tm[srow*512 + sc4];

    // ---- preamble: inline layout probe (waves 0-3) + per-atom loads (waves 4-6) ----
    if (rg < 4) {
        const double af1 = (double)(jl + 1),  bf1 = (double)(jl + 65);
        const double af2 = (double)(1 + ((jl*7 + 3) % 61));
        const double bf2 = (double)(2 + ((jl*13 + 5) % 53));
        dbl4 c1 = {0.0,0.0,0.0,0.0}, c2 = {0.0,0.0,0.0,0.0};
        c1 = __builtin_amdgcn_mfma_f64_16x16x4f64(af1, bf1, c1, 0, 0, 0);
        c2 = __builtin_amdgcn_mfma_f64_16x16x4f64(af2, bf2, c2, 0, 0, 0);
        int myh = -1;
        for (int hh = 0; hh < 8; ++hh) {
            const int h = rg*8 + hh;
            const int pS = h >> 4, pA = (h >> 3) & 1, pB = (h >> 2) & 1, pD = h & 3;
            bool ok = true;
            #pragma unroll
            for (int r = 0; r < 4; ++r) {
                int row, col;
                const int v0 = 4*kl + r, v1 = kl + 4*r;
                if (pD == 0)      { row = v0; col = ml; }
                else if (pD == 1) { row = v1; col = ml; }
                else if (pD == 2) { row = ml; col = v0; }
                else              { row = ml; col = v1; }
                double r1 = 0.0, r2 = 0.0;
                #pragma unroll
                for (int k = 0; k < 4; ++k) {
                    const int la = pA ? (row*4 + k) : (row + 16*k);
                    const int lb = pB ? (col*4 + k) : (col + 16*k);
                    if (pS == 0) {
                        r1 += (double)(la + 1) * (double)(lb + 65);
                        r2 += (double)(1 + ((la*7+3) % 61)) * (double)(2 + ((lb*13+5) % 53));
                    } else {
                        r1 += (double)(lb + 1) * (double)(la + 65);
                        r2 += (double)(1 + ((lb*7+3) % 61)) * (double)(2 + ((la*13+5) % 53));
                    }
                }
                if (c1[r] != r1 || c2[r] != r2) ok = false;
            }
            if (__ballot(ok) == ~0ull) myh = h;
        }
        if (jl == 0) fl_w[rg] = myh;
    } else if (tid >= 256 && tid < 320) {
        const int at = tid - 256;
        posd[3*at+0] = (double)pos[(m*64+at)*3+0];
        posd[3*at+1] = (double)pos[(m*64+at)*3+1];
        posd[3*at+2] = (double)pos[(m*64+at)*3+2];
        double r = (double)covr[an[m*64+at]];
        sig_s[at] = r*r;
        const float* np_ = nattr + (size_t)(m*64+at)*10;
        float best = np_[0]; int bi = 0;
        #pragma unroll
        for (int k = 1; k < 10; ++k) { float vv = np_[k]; if (vv > best) { best = vv; bi = k; } }
        dg_s[at] = (double)hard[bi] + 1.0/(SQRT_PI*r);
    } else if (tid >= 320 && tid < 384) {
        const int at = tid - 320;
        eneg_s[at] = (double)eneg[m*64 + at];
    }
    __syncthreads();   // probe results + atom data ready

    // layout constants (every thread)
    int hbest = max(max(fl_w[0], fl_w[1]), max(fl_w[2], fl_w[3]));
    if (hbest < 0) hbest = 1;   // unreachable on gfx950; standard-layout guess
    const int cS = hbest >> 4, cA = (hbest >> 3) & 1, cB = (hbest >> 2) & 1, cD = hbest & 3;
    const int aRow = cA ? (jl >> 2) : ml;
    const int aK   = cA ? (jl & 3)  : kl;
    const int bRow = cB ? (jl >> 2) : ml;
    const int bK   = cB ? (jl & 3)  : kl;
    int drow[4], dcol[4];
    #pragma unroll
    for (int r = 0; r < 4; ++r) {
        const int v0 = 4*kl + r, v1 = kl + 4*r;
        if (cD == 0)      { drow[r] = v0; dcol[r] = ml; }
        else if (cD == 1) { drow[r] = v1; dcol[r] = ml; }
        else if (cD == 2) { drow[r] = ml; dcol[r] = v0; }
        else              { drow[r] = ml; dcol[r] = v1; }
    }

    // ---- phase B: edge weights w, sqrt(w) (tid<512) ----
    if (tid < 512) {
        const int a0 = eidx[(size_t)m*1024 + tid];
        const int a1 = eidx[(size_t)m*1024 + 512 + tid];
        double dx = posd[3*a0+0]-posd[3*a1+0];
        double dy = posd[3*a0+1]-posd[3*a1+1];
        double dz = posd[3*a0+2]-posd[3*a1+2];
        double d  = sqrt(dx*dx+dy*dy+dz*dz);
        double w  = 1.0 / (1.0/cos(PI_OVER_2RC*d) - 1.0);
        w_sl[tid]  = w;
        rw_sl[tid] = sqrt(w);
    }
    __syncthreads();   // rw visible for prologue staging

    // ---- Gram work assignment: 10 tiles, diag waves {0,5,10,15} full-k,
    //      off-diag pairs split by k-range. wm: 0=kk 0..15, 1=kk 0..7, 2=kk 8..15.
    int tp, tq, wm;
    switch (rg) {
        case 0:  tp=0; tq=0; wm=0; break;
        case 5:  tp=1; tq=1; wm=0; break;
        case 10: tp=2; tq=2; wm=0; break;
        case 15: tp=3; tq=3; wm=0; break;
        case 1:  tp=1; tq=0; wm=1; break;
        case 2:  tp=1; tq=0; wm=2; break;
        case 3:  tp=2; tq=0; wm=1; break;
        case 4:  tp=2; tq=0; wm=2; break;
        case 6:  tp=2; tq=1; wm=1; break;
        case 7:  tp=2; tq=1; wm=2; break;
        case 8:  tp=3; tq=0; wm=1; break;
        case 9:  tp=3; tq=0; wm=2; break;
        case 11: tp=3; tq=1; wm=1; break;
        case 12: tp=3; tq=1; wm=2; break;
        case 13: tp=3; tq=2; wm=1; break;
        default: tp=3; tq=2; wm=2; break;   // rg == 14
    }
    const double* ca_b = &Cd0[(size_t)(tp*16 + aRow)*66 + aK];
    const double* cb_b = &Cd0[(size_t)(tq*16 + bRow)*66 + bK];
    dbl4 vacc = {0.0, 0.0, 0.0, 0.0};
    double t0b_p = 0.0;

    // ---- prologue: stage chunk 0 into Cd0, prefetch chunk 1 ----
    {
        const double r0 = rw_sl[sc4+0], r1 = rw_sl[sc4+1];
        const double r2 = rw_sl[sc4+2], r3 = rw_sl[sc4+3];
        const double c0 = (double)v.x*r0, c1 = (double)v.y*r1;
        const double c2 = (double)v.z*r2, c3 = (double)v.w*r3;
        double2 p0; p0.x = c0; p0.y = c1;
        double2 p1; p1.x = c2; p1.y = c3;
        *(double2*)&Cd0[srow*66 + sc4]     = p0;
        *(double2*)&Cd0[srow*66 + sc4 + 2] = p1;
        t0b_p += c0*r0 + c1*r1 + c2*r2 + c3*r3;
        v = *(const float4*)&Tm[srow*512 + 64 + sc4];
    }
    __syncthreads();   // Cd0 (chunk 0) visible

    #pragma unroll 1
    for (int cc = 0; cc < 8; ++cc) {
        // stage chunk cc+1 into the other buffer (overlaps this chunk's MFMA)
        if (cc < 7) {
            const int e = (cc+1)*64 + sc4;
            const double r0 = rw_sl[e+0], r1 = rw_sl[e+1];
            const double r2 = rw_sl[e+2], r3 = rw_sl[e+3];
            const double c0 = (double)v.x*r0, c1 = (double)v.y*r1;
            const double c2 = (double)v.z*r2, c3 = (double)v.w*r3;
            double* Cw = (((cc+1) & 1) ? Cd1 : Cd0);
            double2 p0; p0.x = c0; p0.y = c1;
            double2 p1; p1.x = c2; p1.y = c3;
            *(double2*)&Cw[srow*66 + sc4]     = p0;
            *(double2*)&Cw[srow*66 + sc4 + 2] = p1;
            t0b_p += c0*r0 + c1*r1 + c2*r2 + c3*r3;
            if (cc < 6) v = *(const float4*)&Tm[srow*512 + (cc+2)*64 + sc4];
        }
        if (cc == 0 && tid >= 128 && tid < 192) {  // wave2: sum(w) (cheap, once)
            const int ll = tid - 128;
            double s = 0.0;
            #pragma unroll
            for (int c = 0; c < 8; ++c) s += w_sl[c*64 + ll];
            #pragma unroll
            for (int off = 32; off > 0; off >>= 1) s += __shfl_down(s, off);
            if (ll == 0) sw_sh = s;
        }
        // ---- symmetric A-build under MFMA shadow: lower triangle only,
        //      linear index t -> (i,j), mirror-write.  2080 entries total:
        //      cc0: t=tid, cc1: t=tid+1024, cc2: t=tid+2048 (tid<32).
        if (cc < 3) {
            int t = -1;
            if (cc == 0) t = tid;
            else if (cc == 1) t = tid + 1024;
            else if (tid < 32) t = tid + 2048;
            if (t >= 0) {
                int i = (int)((sqrt(8.0*(double)t + 1.0) - 1.0) * 0.5);
                if ((i+1)*(i+2)/2 <= t) ++i;     // fix sqrt rounding
                if (i*(i+1)/2 > t) --i;
                const int j = t - i*(i+1)/2;     // j <= i
                double av = a_entry(i, j, posd, sig_s, dg_s);
                AB[i*65 + j] = av;
                AB[j*65 + i] = av;
            }
        }
        const int bo = (cc & 1) * 4224;            // current buffer offset (elements)
        if (wm == 0) {
            #pragma unroll
            for (int kk = 0; kk < 16; ++kk)
                vacc = mfma64(cS, ca_b[bo + kk*4], cb_b[bo + kk*4], vacc);
        } else if (wm == 1) {
            #pragma unroll
            for (int kk = 0; kk < 8; ++kk)
                vacc = mfma64(cS, ca_b[bo + kk*4], cb_b[bo + kk*4], vacc);
        } else {
            #pragma unroll
            for (int kk = 8; kk < 16; ++kk)
                vacc = mfma64(cS, ca_b[bo + kk*4], cb_b[bo + kk*4], vacc);
        }
        __syncthreads();   // reads of buf[cc&1] done; staged chunk cc+1 visible
    }
    // last loop barrier doubles as the gram->SB transition barrier

    // ---- S assembly: full/first-half writers first, second-half adders second ----
    if (wm != 2) {
        #pragma unroll
        for (int r = 0; r < 4; ++r) {
            const int ri = tp*16 + drow[r], cj = tq*16 + dcol[r];
            SB[ri*66 + cj] = vacc[r];
            if (tp != tq) SB[cj*66 + ri] = vacc[r];
        }
    }
    {   // t0b: reduce 16 column-group partials per row (register-only)
        double t = t0b_p;
        t += __shfl_down(t, 8, 16);
        t += __shfl_down(t, 4, 16);
        t += __shfl_down(t, 2, 16);
        t += __shfl_down(t, 1, 16);
        if ((tid & 15) == 0) t0b_s[tid >> 4] = t;
    }
    __syncthreads();
    if (wm == 2) {
        #pragma unroll
        for (int r = 0; r < 4; ++r) {
            const int ri = tp*16 + drow[r], cj = tq*16 + dcol[r];
            const double vv = vacc[r];
            SB[ri*66 + cj] += vv;
            if (tp != tq) SB[cj*66 + ri] += vv;
        }
    }
    __syncthreads();   // S complete

    // ---- t0a = -S·eneg (LDS-S, 16-lane reduce) ----
    {
        const int c16 = tid & 15, row16 = tid >> 4;
        double a = 0.0;
        #pragma unroll
        for (int kk = 0; kk < 4; ++kk)
            a += SB[row16*66 + 4*c16 + kk] * eneg_s[4*c16 + kk];
        a += __shfl_down(a, 8, 16);
        a += __shfl_down(a, 4, 16);
        a += __shfl_down(a, 2, 16);
        a += __shfl_down(a, 1, 16);
        if (c16 == 0) t0a_s[row16] = -a;
    }
    __syncthreads();

    // ---- g = A·t0 via wave reduction (A-column read back from LDS) ----
    {
        const double areg0 = AB[(rg+ 0)*65 + jl];
        const double areg1 = AB[(rg+16)*65 + jl];
        const double areg2 = AB[(rg+32)*65 + jl];
        const double areg3 = AB[(rg+48)*65 + jl];
        const double ta = t0a_s[jl], tb = t0b_s[jl];
        double ra0 = areg0*ta, ra1 = areg1*ta, ra2 = areg2*ta, ra3 = areg3*ta;
        double rb0 = areg0*tb, rb1 = areg1*tb, rb2 = areg2*tb, rb3 = areg3*tb;
        #pragma unroll
        for (int off = 32; off > 0; off >>= 1) {
            ra0 += __shfl_down(ra0, off); ra1 += __shfl_down(ra1, off);
            ra2 += __shfl_down(ra2, off); ra3 += __shfl_down(ra3, off);
            rb0 += __shfl_down(rb0, off); rb1 += __shfl_down(rb1, off);
            rb2 += __shfl_down(rb2, off); rb3 += __shfl_down(rb3, off);
        }
        if (jl == 0) {
            ga_s[rg+ 0] = ra0; ga_s[rg+16] = ra1; ga_s[rg+32] = ra2; ga_s[rg+48] = ra3;
            gb_s[rg+ 0] = rb0; gb_s[rg+16] = rb1; gb_s[rg+32] = rb2; gb_s[rg+48] = rb3;
        }
    }
    __syncthreads();

    // ---- GEMM1: P = A·S (16 tiles / 16 waves, immediate-offset operands) ----
    const int ti = rg >> 2, tj = rg & 3;
    {
        const double* xb = &AB[(size_t)(ti*16 + aRow)*65 + aK];
        const double* yb = &SB[(size_t)bK*66 + tj*16 + bRow];
        dbl4 pacc = {0.0, 0.0, 0.0, 0.0};
        #pragma unroll
        for (int kk = 0; kk < 16; ++kk)
            pacc = mfma64(cS, xb[kk*4], yb[kk*264], pacc);
        #pragma unroll
        for (int r = 0; r < 4; ++r)
            Pm[(ti*16 + drow[r])*66 + tj*16 + dcol[r]] = pacc[r];   // Pm != SB, no barrier needed
    }
    __syncthreads();   // P visible

    // ---- GEMM2: M = A + P·A, overwrite AB ----
    {
        dbl4 macc;
        #pragma unroll
        for (int r = 0; r < 4; ++r)
            macc[r] = AB[(ti*16 + drow[r])*65 + tj*16 + dcol[r]];
        const double* xb = &Pm[(size_t)(ti*16 + aRow)*66 + aK];
        const double* yb = &AB[(size_t)bK*65 + tj*16 + bRow];
        #pragma unroll
        for (int kk = 0; kk < 16; ++kk)
            macc = mfma64(cS, xb[kk*4], yb[kk*260], macc);
        __syncthreads();   // all GEMM2 AB reads done
        #pragma unroll
        for (int r = 0; r < 4; ++r)
            AB[(ti*16 + drow[r])*65 + tj*16 + dcol[r]] = macc[r];
    }
    __syncthreads();

    // ---- blocked LDL^T: wave0 panel factor + trailing updates (verified) ----
    for (int pb = 0; pb < 4; ++pb) {
        const int kb = pb*16;
        if (tid < 64) {
            const int i = tid;
            double pr[16];
            #pragma unroll
            for (int c = 0; c < 16; ++c) pr[c] = AB[i*65 + kb + c];
            #pragma unroll
            for (int c = 0; c < 16; ++c) {
                const int k = kb + c;
                const double Dk = bcast64(pr[c], k);
                const double di = 1.0 / Dk;
                if (i == k) { dinv_s[k] = di; dvec_s[k] = Dk; }
                const double lik = pr[c] * di;
                #pragma unroll
                for (int j = c+1; j < 16; ++j) {
                    const double mkj = bcast64(pr[j], k);
                    if (i > k) pr[j] -= lik * mkj;
                }
                if (i > k) pr[c] = lik;
            }
            #pragma unroll
            for (int c = 0; c < 16; ++c) AB[i*65 + kb + c] = pr[c];
        }
        __syncthreads();
        const int lim = kb + 16;
        if (lim < 64) {
            double tacc[4] = {0.0, 0.0, 0.0, 0.0};
            #pragma unroll 4
            for (int c = 0; c < 16; ++c) {
                double lbv = AB[jl*65 + kb + c] * dvec_s[kb + c];
                #pragma unroll
                for (int p = 0; p < 4; ++p)
                    tacc[p] += AB[(rg+16*p)*65 + kb + c] * lbv;
            }
            if (jl >= lim) {
                #pragma unroll
                for (int p = 0; p < 4; ++p) {
                    int i = rg + 16*p;
                    if (i >= lim) AB[i*65 + jl] -= tacc[p];
                }
            }
        }
        __syncthreads();
    }

    // ---- solves: wave0 does RHS a, wave1 does RHS b (independent chains) ----
    if (tid < 128) {
        const int i = jl;
        double h = (rg == 0) ? ga_s[i] : gb_s[i];
        #pragma unroll
        for (int j = 0; j < 63; ++j) {
            double x = bcast64(h, j);
            double lij = (i > j) ? AB[i*65+j] : 0.0;
            h -= lij*x;
        }
        h *= dinv_s[i];
        #pragma unroll
        for (int j = 63; j > 0; --j) {
            double x = bcast64(h, j);
            double lji = (i < j) ? AB[j*65+i] : 0.0;
            h -= lji*x;
        }
        if (rg == 0) ua_s[i] = h; else ub_s[i] = h;
    }
    __syncthreads();

    // ---- lambda (identities: sa.t0b = ua.gb, sb.t0b = ub.gb), via lam_sh ----
    if (tid < 64) {
        const double ua = ua_s[tid], ub = ub_s[tid], gbv = gb_s[tid];
        double d1 = eneg_s[tid]*t0b_s[tid] + ua*gbv;   // = (eneg + sa)·t0b termwise
        double d2 = ub*gbv;                            // = sb·t0b termwise
        #pragma unroll
        for (int off = 32; off > 0; off >>= 1) {
            d1 += __shfl_down(d1, off);
            d2 += __shfl_down(d2, off);
        }
        if (tid == 0) {
            double sY = -d1;
            double sZ = sw_sh - d2;
            lam_sh = ((double)qtot[m] - sY) / (1.0 - sZ);
        }
    }
    __syncthreads();
    if (tid < 64)
        outp[m*64 + tid] = (float)(ua_s[tid] - lam_sh*ub_s[tid]);
}

extern "C" void kernel_launch(void* const* d_in, const int* in_sizes, int n_in,
                              void* d_out, int out_size, void* d_ws, size_t ws_size,
                              hipStream_t stream) {
    const float* pos  = (const float*)d_in[0];
    const float* T    = (const float*)d_in[1];
    const float* eneg = (const float*)d_in[2];
    const float* nat  = (const float*)d_in[3];
    const float* qt   = (const float*)d_in[4];
    // d_in[5] 'p' unused
    const float* hard = (const float*)d_in[6];
    const float* covr = (const float*)d_in[7];
    const int*   an   = (const int*)d_in[8];
    const int*   eidx = (const int*)d_in[9];
    float* outp = (float*)d_out;
    (void)n_in; (void)out_size; (void)d_ws; (void)ws_size;

    const int B = in_sizes[4];
    k_fused<<<dim3(B), dim3(1024), 0, stream>>>(pos, T, eidx, nat, eneg, qt,
                                                hard, covr, an, outp);
}

// Round 15
// 151.646 us; speedup vs baseline: 1.1486x; 1.0115x over previous
//
#include <hip/hip_runtime.h>
#include <math.h>

// Problem constants: B molecules, N=64 atoms, E=512 edges, R_CUT=10
#define SQRT_PI 1.7724538509055160273
#define SQRT_2  1.4142135623730950488
#define PI_OVER_2RC 0.15707963267948966

typedef double dbl4 __attribute__((ext_vector_type(4)));

__device__ __forceinline__ double bcast64(double v, int lane) {
    union { double d; unsigned int u[2]; } a, r;
    a.d = v;
    r.u[0] = __builtin_amdgcn_readlane(a.u[0], lane);
    r.u[1] = __builtin_amdgcn_readlane(a.u[1], lane);
    return r.d;
}

__device__ __forceinline__ double a_entry(int i, int j, const double* posd,
                                          const double* sig, const double* dg) {
    if (i == j) return dg[i];
    double dx = posd[3*i+0]-posd[3*j+0];
    double dy = posd[3*i+1]-posd[3*j+1];
    double dz = posd[3*i+2]-posd[3*j+2];
    double d  = sqrt(dx*dx+dy*dy+dz*dz);
    double g  = sqrt(sig[i]+sig[j]);
    return erf(d/(SQRT_2*g))/d;
}

// swap-aware MFMA: xv = A-side value, yv = B-side value
__device__ __forceinline__ dbl4 mfma64(int cS, double xv, double yv, dbl4 acc) {
    return cS ? __builtin_amdgcn_mfma_f64_16x16x4f64(yv, xv, acc, 0, 0, 0)
              : __builtin_amdgcn_mfma_f64_16x16x4f64(xv, yv, acc, 0, 0, 0);
}

// ---------------- fused kernel (SINGLE dispatch) ----------------
// one block (16 waves) per molecule.  BASE = round-14 verified structure
// (71.4 us, end-to-end 153.4): inline MFMA-layout probe (waves 0-3) +
// atom loads (waves 4-6) in preamble; double-buffered single-factor gram
// (S = C C^T, C = T*sqrt(w), ping-pong Cd0/Cd1, one barrier/chunk,
// `#pragma unroll 1` fences the pipeliner -> no spill); k-range tile split;
// parallel two-RHS solves; lambda identities.  ONE change vs round 14:
//   A-build moved OUT of the gram loop into phase B: all 1024 threads
//   build the 2080 lower-triangle entries (~2 each, mirror-write)
//   concurrently with the w-computation (threads 0-511).  Gram chunks
//   become pure stage+MFMA -- the per-chunk barrier no longer waits on
//   erf chains in the slowest wave.
// Identity 1: out = u; Identity 2: sa.t0b = ua.gb, sb.t0b = ub.gb.
// Lambda via lam_sh + barrier (in-register bcast of conditionally-assigned
// value miscompiled in round 5).
__global__ __launch_bounds__(1024)
void k_fused(const float* __restrict__ pos, const float* __restrict__ T,
             const int* __restrict__ eidx, const float* __restrict__ nattr,
             const float* __restrict__ eneg, const float* __restrict__ qtot,
             const float* __restrict__ hard, const float* __restrict__ covr,
             const int* __restrict__ an, float* __restrict__ outp)
{
    const int m = blockIdx.x, tid = threadIdx.x;
    const int jl = tid & 63;        // lane
    const int rg = tid >> 6;        // wave id 0..15
    const int kl = jl >> 4, ml = jl & 15;

    __shared__ double R[2*64*66];   // Cd0,Cd1 | SB,Pm   (67584 B)
    __shared__ double AB[64*65];    // A then M/L        (33280 B)
    __shared__ double w_sl[512];    // w
    __shared__ double rw_sl[512];   // sqrt(w)
    __shared__ double posd[192], sig_s[64], dg_s[64], eneg_s[64];
    __shared__ double t0a_s[64], t0b_s[64], ga_s[64], gb_s[64];
    __shared__ double ua_s[64], ub_s[64];
    __shared__ double dinv_s[64], dvec_s[64];
    __shared__ double lam_sh, sw_sh;
    __shared__ int fl_w[4];

    double* const Cd0 = R;          // [64][66] f64, gram ping buffer
    double* const Cd1 = R + 64*66;  // [64][66] f64, gram pong buffer
    double* const SB = R;           // [64][66] f64, S (post-gram .. end)
    double* const Pm = R + 64*66;   // [64][66] f64, P = A*S

    const float* Tm = T + (size_t)m*64*512;
    const int srow = tid >> 4, sc4 = (tid & 15) * 4;

    // earliest possible chunk-0 prefetch
    float4 v = *(const float4*)&Tm[srow*512 + sc4];

    // ---- preamble: inline layout probe (waves 0-3) + per-atom loads (waves 4-6) ----
    if (rg < 4) {
        const double af1 = (double)(jl + 1),  bf1 = (double)(jl + 65);
        const double af2 = (double)(1 + ((jl*7 + 3) % 61));
        const double bf2 = (double)(2 + ((jl*13 + 5) % 53));
        dbl4 c1 = {0.0,0.0,0.0,0.0}, c2 = {0.0,0.0,0.0,0.0};
        c1 = __builtin_amdgcn_mfma_f64_16x16x4f64(af1, bf1, c1, 0, 0, 0);
        c2 = __builtin_amdgcn_mfma_f64_16x16x4f64(af2, bf2, c2, 0, 0, 0);
        int myh = -1;
        for (int hh = 0; hh < 8; ++hh) {
            const int h = rg*8 + hh;
            const int pS = h >> 4, pA = (h >> 3) & 1, pB = (h >> 2) & 1, pD = h & 3;
            bool ok = true;
            #pragma unroll
            for (int r = 0; r < 4; ++r) {
                int row, col;
                const int v0 = 4*kl + r, v1 = kl + 4*r;
                if (pD == 0)      { row = v0; col = ml; }
                else if (pD == 1) { row = v1; col = ml; }
                else if (pD == 2) { row = ml; col = v0; }
                else              { row = ml; col = v1; }
                double r1 = 0.0, r2 = 0.0;
                #pragma unroll
                for (int k = 0; k < 4; ++k) {
                    const int la = pA ? (row*4 + k) : (row + 16*k);
                    const int lb = pB ? (col*4 + k) : (col + 16*k);
                    if (pS == 0) {
                        r1 += (double)(la + 1) * (double)(lb + 65);
                        r2 += (double)(1 + ((la*7+3) % 61)) * (double)(2 + ((lb*13+5) % 53));
                    } else {
                        r1 += (double)(lb + 1) * (double)(la + 65);
                        r2 += (double)(1 + ((lb*7+3) % 61)) * (double)(2 + ((la*13+5) % 53));
                    }
                }
                if (c1[r] != r1 || c2[r] != r2) ok = false;
            }
            if (__ballot(ok) == ~0ull) myh = h;
        }
        if (jl == 0) fl_w[rg] = myh;
    } else if (tid >= 256 && tid < 320) {
        const int at = tid - 256;
        posd[3*at+0] = (double)pos[(m*64+at)*3+0];
        posd[3*at+1] = (double)pos[(m*64+at)*3+1];
        posd[3*at+2] = (double)pos[(m*64+at)*3+2];
        double r = (double)covr[an[m*64+at]];
        sig_s[at] = r*r;
        const float* np_ = nattr + (size_t)(m*64+at)*10;
        float best = np_[0]; int bi = 0;
        #pragma unroll
        for (int k = 1; k < 10; ++k) { float vv = np_[k]; if (vv > best) { best = vv; bi = k; } }
        dg_s[at] = (double)hard[bi] + 1.0/(SQRT_PI*r);
    } else if (tid >= 320 && tid < 384) {
        const int at = tid - 320;
        eneg_s[at] = (double)eneg[m*64 + at];
    }
    __syncthreads();   // probe results + atom data ready

    // layout constants (every thread)
    int hbest = max(max(fl_w[0], fl_w[1]), max(fl_w[2], fl_w[3]));
    if (hbest < 0) hbest = 1;   // unreachable on gfx950; standard-layout guess
    const int cS = hbest >> 4, cA = (hbest >> 3) & 1, cB = (hbest >> 2) & 1, cD = hbest & 3;
    const int aRow = cA ? (jl >> 2) : ml;
    const int aK   = cA ? (jl & 3)  : kl;
    const int bRow = cB ? (jl >> 2) : ml;
    const int bK   = cB ? (jl & 3)  : kl;
    int drow[4], dcol[4];
    #pragma unroll
    for (int r = 0; r < 4; ++r) {
        const int v0 = 4*kl + r, v1 = kl + 4*r;
        if (cD == 0)      { drow[r] = v0; dcol[r] = ml; }
        else if (cD == 1) { drow[r] = v1; dcol[r] = ml; }
        else if (cD == 2) { drow[r] = ml; dcol[r] = v0; }
        else              { drow[r] = ml; dcol[r] = v1; }
    }

    // ---- phase B: edge weights (tid<512) + FULL symmetric A-build (all threads) ----
    if (tid < 512) {
        const int a0 = eidx[(size_t)m*1024 + tid];
        const int a1 = eidx[(size_t)m*1024 + 512 + tid];
        double dx = posd[3*a0+0]-posd[3*a1+0];
        double dy = posd[3*a0+1]-posd[3*a1+1];
        double dz = posd[3*a0+2]-posd[3*a1+2];
        double d  = sqrt(dx*dx+dy*dy+dz*dz);
        double w  = 1.0 / (1.0/cos(PI_OVER_2RC*d) - 1.0);
        w_sl[tid]  = w;
        rw_sl[tid] = sqrt(w);
    }
    // lower triangle: 2080 entries, linear index t -> (i,j), mirror-write.
    #pragma unroll
    for (int q = 0; q < 3; ++q) {
        int t;
        if (q == 0) t = tid;
        else if (q == 1) t = tid + 1024;
        else t = (tid < 32) ? (tid + 2048) : -1;
        if (t >= 0) {
            int i = (int)((sqrt(8.0*(double)t + 1.0) - 1.0) * 0.5);
            if ((i+1)*(i+2)/2 <= t) ++i;     // fix sqrt rounding
            if (i*(i+1)/2 > t) --i;
            const int j = t - i*(i+1)/2;     // j <= i
            double av = a_entry(i, j, posd, sig_s, dg_s);
            AB[i*65 + j] = av;
            AB[j*65 + i] = av;
        }
    }
    __syncthreads();   // w/rw + A visible

    // ---- Gram work assignment: 10 tiles, diag waves {0,5,10,15} full-k,
    //      off-diag pairs split by k-range. wm: 0=kk 0..15, 1=kk 0..7, 2=kk 8..15.
    int tp, tq, wm;
    switch (rg) {
        case 0:  tp=0; tq=0; wm=0; break;
        case 5:  tp=1; tq=1; wm=0; break;
        case 10: tp=2; tq=2; wm=0; break;
        case 15: tp=3; tq=3; wm=0; break;
        case 1:  tp=1; tq=0; wm=1; break;
        case 2:  tp=1; tq=0; wm=2; break;
        case 3:  tp=2; tq=0; wm=1; break;
        case 4:  tp=2; tq=0; wm=2; break;
        case 6:  tp=2; tq=1; wm=1; break;
        case 7:  tp=2; tq=1; wm=2; break;
        case 8:  tp=3; tq=0; wm=1; break;
        case 9:  tp=3; tq=0; wm=2; break;
        case 11: tp=3; tq=1; wm=1; break;
        case 12: tp=3; tq=1; wm=2; break;
        case 13: tp=3; tq=2; wm=1; break;
        default: tp=3; tq=2; wm=2; break;   // rg == 14
    }
    const double* ca_b = &Cd0[(size_t)(tp*16 + aRow)*66 + aK];
    const double* cb_b = &Cd0[(size_t)(tq*16 + bRow)*66 + bK];
    dbl4 vacc = {0.0, 0.0, 0.0, 0.0};
    double t0b_p = 0.0;

    // ---- prologue: stage chunk 0 into Cd0, prefetch chunk 1 ----
    {
        const double r0 = rw_sl[sc4+0], r1 = rw_sl[sc4+1];
        const double r2 = rw_sl[sc4+2], r3 = rw_sl[sc4+3];
        const double c0 = (double)v.x*r0, c1 = (double)v.y*r1;
        const double c2 = (double)v.z*r2, c3 = (double)v.w*r3;
        double2 p0; p0.x = c0; p0.y = c1;
        double2 p1; p1.x = c2; p1.y = c3;
        *(double2*)&Cd0[srow*66 + sc4]     = p0;
        *(double2*)&Cd0[srow*66 + sc4 + 2] = p1;
        t0b_p += c0*r0 + c1*r1 + c2*r2 + c3*r3;
        v = *(const float4*)&Tm[srow*512 + 64 + sc4];
    }
    __syncthreads();   // Cd0 (chunk 0) visible

    #pragma unroll 1
    for (int cc = 0; cc < 8; ++cc) {
        // stage chunk cc+1 into the other buffer (overlaps this chunk's MFMA)
        if (cc < 7) {
            const int e = (cc+1)*64 + sc4;
            const double r0 = rw_sl[e+0], r1 = rw_sl[e+1];
            const double r2 = rw_sl[e+2], r3 = rw_sl[e+3];
            const double c0 = (double)v.x*r0, c1 = (double)v.y*r1;
            const double c2 = (double)v.z*r2, c3 = (double)v.w*r3;
            double* Cw = (((cc+1) & 1) ? Cd1 : Cd0);
            double2 p0; p0.x = c0; p0.y = c1;
            double2 p1; p1.x = c2; p1.y = c3;
            *(double2*)&Cw[srow*66 + sc4]     = p0;
            *(double2*)&Cw[srow*66 + sc4 + 2] = p1;
            t0b_p += c0*r0 + c1*r1 + c2*r2 + c3*r3;
            if (cc < 6) v = *(const float4*)&Tm[srow*512 + (cc+2)*64 + sc4];
        }
        if (cc == 0 && tid >= 128 && tid < 192) {  // wave2: sum(w) (cheap, once)
            const int ll = tid - 128;
            double s = 0.0;
            #pragma unroll
            for (int c = 0; c < 8; ++c) s += w_sl[c*64 + ll];
            #pragma unroll
            for (int off = 32; off > 0; off >>= 1) s += __shfl_down(s, off);
            if (ll == 0) sw_sh = s;
        }
        const int bo = (cc & 1) * 4224;            // current buffer offset (elements)
        if (wm == 0) {
            #pragma unroll
            for (int kk = 0; kk < 16; ++kk)
                vacc = mfma64(cS, ca_b[bo + kk*4], cb_b[bo + kk*4], vacc);
        } else if (wm == 1) {
            #pragma unroll
            for (int kk = 0; kk < 8; ++kk)
                vacc = mfma64(cS, ca_b[bo + kk*4], cb_b[bo + kk*4], vacc);
        } else {
            #pragma unroll
            for (int kk = 8; kk < 16; ++kk)
                vacc = mfma64(cS, ca_b[bo + kk*4], cb_b[bo + kk*4], vacc);
        }
        __syncthreads();   // reads of buf[cc&1] done; staged chunk cc+1 visible
    }
    // last loop barrier doubles as the gram->SB transition barrier

    // ---- S assembly: full/first-half writers first, second-half adders second ----
    if (wm != 2) {
        #pragma unroll
        for (int r = 0; r < 4; ++r) {
            const int ri = tp*16 + drow[r], cj = tq*16 + dcol[r];
            SB[ri*66 + cj] = vacc[r];
            if (tp != tq) SB[cj*66 + ri] = vacc[r];
        }
    }
    {   // t0b: reduce 16 column-group partials per row (register-only)
        double t = t0b_p;
        t += __shfl_down(t, 8, 16);
        t += __shfl_down(t, 4, 16);
        t += __shfl_down(t, 2, 16);
        t += __shfl_down(t, 1, 16);
        if ((tid & 15) == 0) t0b_s[tid >> 4] = t;
    }
    __syncthreads();
    if (wm == 2) {
        #pragma unroll
        for (int r = 0; r < 4; ++r) {
            const int ri = tp*16 + drow[r], cj = tq*16 + dcol[r];
            const double vv = vacc[r];
            SB[ri*66 + cj] += vv;
            if (tp != tq) SB[cj*66 + ri] += vv;
        }
    }
    __syncthreads();   // S complete

    // ---- t0a = -S·eneg (LDS-S, 16-lane reduce) ----
    {
        const int c16 = tid & 15, row16 = tid >> 4;
        double a = 0.0;
        #pragma unroll
        for (int kk = 0; kk < 4; ++kk)
            a += SB[row16*66 + 4*c16 + kk] * eneg_s[4*c16 + kk];
        a += __shfl_down(a, 8, 16);
        a += __shfl_down(a, 4, 16);
        a += __shfl_down(a, 2, 16);
        a += __shfl_down(a, 1, 16);
        if (c16 == 0) t0a_s[row16] = -a;
    }
    __syncthreads();

    // ---- g = A·t0 via wave reduction (A-column read from LDS) ----
    {
        const double areg0 = AB[(rg+ 0)*65 + jl];
        const double areg1 = AB[(rg+16)*65 + jl];
        const double areg2 = AB[(rg+32)*65 + jl];
        const double areg3 = AB[(rg+48)*65 + jl];
        const double ta = t0a_s[jl], tb = t0b_s[jl];
        double ra0 = areg0*ta, ra1 = areg1*ta, ra2 = areg2*ta, ra3 = areg3*ta;
        double rb0 = areg0*tb, rb1 = areg1*tb, rb2 = areg2*tb, rb3 = areg3*tb;
        #pragma unroll
        for (int off = 32; off > 0; off >>= 1) {
            ra0 += __shfl_down(ra0, off); ra1 += __shfl_down(ra1, off);
            ra2 += __shfl_down(ra2, off); ra3 += __shfl_down(ra3, off);
            rb0 += __shfl_down(rb0, off); rb1 += __shfl_down(rb1, off);
            rb2 += __shfl_down(rb2, off); rb3 += __shfl_down(rb3, off);
        }
        if (jl == 0) {
            ga_s[rg+ 0] = ra0; ga_s[rg+16] = ra1; ga_s[rg+32] = ra2; ga_s[rg+48] = ra3;
            gb_s[rg+ 0] = rb0; gb_s[rg+16] = rb1; gb_s[rg+32] = rb2; gb_s[rg+48] = rb3;
        }
    }
    __syncthreads();

    // ---- GEMM1: P = A·S (16 tiles / 16 waves, immediate-offset operands) ----
    const int ti = rg >> 2, tj = rg & 3;
    {
        const double* xb = &AB[(size_t)(ti*16 + aRow)*65 + aK];
        const double* yb = &SB[(size_t)bK*66 + tj*16 + bRow];
        dbl4 pacc = {0.0, 0.0, 0.0, 0.0};
        #pragma unroll
        for (int kk = 0; kk < 16; ++kk)
            pacc = mfma64(cS, xb[kk*4], yb[kk*264], pacc);
        #pragma unroll
        for (int r = 0; r < 4; ++r)
            Pm[(ti*16 + drow[r])*66 + tj*16 + dcol[r]] = pacc[r];   // Pm != SB, no barrier needed
    }
    __syncthreads();   // P visible

    // ---- GEMM2: M = A + P·A, overwrite AB ----
    {
        dbl4 macc;
        #pragma unroll
        for (int r = 0; r < 4; ++r)
            macc[r] = AB[(ti*16 + drow[r])*65 + tj*16 + dcol[r]];
        const double* xb = &Pm[(size_t)(ti*16 + aRow)*66 + aK];
        const double* yb = &AB[(size_t)bK*65 + tj*16 + bRow];
        #pragma unroll
        for (int kk = 0; kk < 16; ++kk)
            macc = mfma64(cS, xb[kk*4], yb[kk*260], macc);
        __syncthreads();   // all GEMM2 AB reads done
        #pragma unroll
        for (int r = 0; r < 4; ++r)
            AB[(ti*16 + drow[r])*65 + tj*16 + dcol[r]] = macc[r];
    }
    __syncthreads();

    // ---- blocked LDL^T: wave0 panel factor + trailing updates (verified) ----
    for (int pb = 0; pb < 4; ++pb) {
        const int kb = pb*16;
        if (tid < 64) {
            const int i = tid;
            double pr[16];
            #pragma unroll
            for (int c = 0; c < 16; ++c) pr[c] = AB[i*65 + kb + c];
            #pragma unroll
            for (int c = 0; c < 16; ++c) {
                const int k = kb + c;
                const double Dk = bcast64(pr[c], k);
                const double di = 1.0 / Dk;
                if (i == k) { dinv_s[k] = di; dvec_s[k] = Dk; }
                const double lik = pr[c] * di;
                #pragma unroll
                for (int j = c+1; j < 16; ++j) {
                    const double mkj = bcast64(pr[j], k);
                    if (i > k) pr[j] -= lik * mkj;
                }
                if (i > k) pr[c] = lik;
            }
            #pragma unroll
            for (int c = 0; c < 16; ++c) AB[i*65 + kb + c] = pr[c];
        }
        __syncthreads();
        const int lim = kb + 16;
        if (lim < 64) {
            double tacc[4] = {0.0, 0.0, 0.0, 0.0};
            #pragma unroll 4
            for (int c = 0; c < 16; ++c) {
                double lbv = AB[jl*65 + kb + c] * dvec_s[kb + c];
                #pragma unroll
                for (int p = 0; p < 4; ++p)
                    tacc[p] += AB[(rg+16*p)*65 + kb + c] * lbv;
            }
            if (jl >= lim) {
                #pragma unroll
                for (int p = 0; p < 4; ++p) {
                    int i = rg + 16*p;
                    if (i >= lim) AB[i*65 + jl] -= tacc[p];
                }
            }
        }
        __syncthreads();
    }

    // ---- solves: wave0 does RHS a, wave1 does RHS b (independent chains) ----
    if (tid < 128) {
        const int i = jl;
        double h = (rg == 0) ? ga_s[i] : gb_s[i];
        #pragma unroll
        for (int j = 0; j < 63; ++j) {
            double x = bcast64(h, j);
            double lij = (i > j) ? AB[i*65+j] : 0.0;
            h -= lij*x;
        }
        h *= dinv_s[i];
        #pragma unroll
        for (int j = 63; j > 0; --j) {
            double x = bcast64(h, j);
            double lji = (i < j) ? AB[j*65+i] : 0.0;
            h -= lji*x;
        }
        if (rg == 0) ua_s[i] = h; else ub_s[i] = h;
    }
    __syncthreads();

    // ---- lambda (identities: sa.t0b = ua.gb, sb.t0b = ub.gb), via lam_sh ----
    if (tid < 64) {
        const double ua = ua_s[tid], ub = ub_s[tid], gbv = gb_s[tid];
        double d1 = eneg_s[tid]*t0b_s[tid] + ua*gbv;   // = (eneg + sa)·t0b termwise
        double d2 = ub*gbv;                            // = sb·t0b termwise
        #pragma unroll
        for (int off = 32; off > 0; off >>= 1) {
            d1 += __shfl_down(d1, off);
            d2 += __shfl_down(d2, off);
        }
        if (tid == 0) {
            double sY = -d1;
            double sZ = sw_sh - d2;
            lam_sh = ((double)qtot[m] - sY) / (1.0 - sZ);
        }
    }
    __syncthreads();
    if (tid < 64)
        outp[m*64 + tid] = (float)(ua_s[tid] - lam_sh*ub_s[tid]);
}

extern "C" void kernel_launch(void* const* d_in, const int* in_sizes, int n_in,
                              void* d_out, int out_size, void* d_ws, size_t ws_size,
                              hipStream_t stream) {
    const float* pos  = (const float*)d_in[0];
    const float* T    = (const float*)d_in[1];
    const float* eneg = (const float*)d_in[2];
    const float* nat  = (const float*)d_in[3];
    const float* qt   = (const float*)d_in[4];
    // d_in[5] 'p' unused
    const float* hard = (const float*)d_in[6];
    const float* covr = (const float*)d_in[7];
    const int*   an   = (const int*)d_in[8];
    const int*   eidx = (const int*)d_in[9];
    float* outp = (float*)d_out;
    (void)n_in; (void)out_size; (void)d_ws; (void)ws_size;

    const int B = in_sizes[4];
    k_fused<<<dim3(B), dim3(1024), 0, stream>>>(pos, T, eidx, nat, eneg, qt,
                                                hard, covr, an, outp);
}

// Round 16
// 150.015 us; speedup vs baseline: 1.1611x; 1.0109x over previous
//
#include <hip/hip_runtime.h>
#include <math.h>

// Problem constants: B molecules, N=64 atoms, E=512 edges, R_CUT=10
#define SQRT_PI 1.7724538509055160273
#define SQRT_2  1.4142135623730950488
#define PI_OVER_2RC 0.15707963267948966

typedef double dbl4 __attribute__((ext_vector_type(4)));

__device__ __forceinline__ double bcast64(double v, int lane) {
    union { double d; unsigned int u[2]; } a, r;
    a.d = v;
    r.u[0] = __builtin_amdgcn_readlane(a.u[0], lane);
    r.u[1] = __builtin_amdgcn_readlane(a.u[1], lane);
    return r.d;
}

__device__ __forceinline__ double a_entry(int i, int j, const double* posd,
                                          const double* sig, const double* dg) {
    if (i == j) return dg[i];
    double dx = posd[3*i+0]-posd[3*j+0];
    double dy = posd[3*i+1]-posd[3*j+1];
    double dz = posd[3*i+2]-posd[3*j+2];
    double d  = sqrt(dx*dx+dy*dy+dz*dz);
    double g  = sqrt(sig[i]+sig[j]);
    return erf(d/(SQRT_2*g))/d;
}

// swap-aware MFMA: xv = A-side value, yv = B-side value
__device__ __forceinline__ dbl4 mfma64(int cS, double xv, double yv, dbl4 acc) {
    return cS ? __builtin_amdgcn_mfma_f64_16x16x4f64(yv, xv, acc, 0, 0, 0)
              : __builtin_amdgcn_mfma_f64_16x16x4f64(xv, yv, acc, 0, 0, 0);
}

// ---------------- fused kernel (SINGLE dispatch) ----------------
// one block (16 waves) per molecule.  BASE = round-15 verified structure
// (70.2 us, end-to-end 151.6): double-buffered single-factor gram
// (S = C C^T, C = T*sqrt(w), ping-pong Cd0/Cd1, one barrier/chunk,
// `#pragma unroll 1` fences the pipeliner -> no spill); k-range tile split;
// symmetric lower-triangle A-build; parallel two-RHS solves; lambda
// identities.  ONE change vs round 15:
//   Layout probe moved INTO phase B: waves 0-3 probe while tid 256-767
//   compute w and tid 256-1023 build A (3 triangle entries each).  The
//   probe's ~1.5 us leaves the critical path (was a dedicated preamble
//   phase); preamble shrinks to atom loads only.  Layout constants are
//   derived after the phase-B barrier.
// Identity 1: out = u; Identity 2: sa.t0b = ua.gb, sb.t0b = ub.gb.
// Lambda via lam_sh + barrier (in-register bcast of conditionally-assigned
// value miscompiled in round 5).
__global__ __launch_bounds__(1024)
void k_fused(const float* __restrict__ pos, const float* __restrict__ T,
             const int* __restrict__ eidx, const float* __restrict__ nattr,
             const float* __restrict__ eneg, const float* __restrict__ qtot,
             const float* __restrict__ hard, const float* __restrict__ covr,
             const int* __restrict__ an, float* __restrict__ outp)
{
    const int m = blockIdx.x, tid = threadIdx.x;
    const int jl = tid & 63;        // lane
    const int rg = tid >> 6;        // wave id 0..15
    const int kl = jl >> 4, ml = jl & 15;

    __shared__ double R[2*64*66];   // Cd0,Cd1 | SB,Pm   (67584 B)
    __shared__ double AB[64*65];    // A then M/L        (33280 B)
    __shared__ double w_sl[512];    // w
    __shared__ double rw_sl[512];   // sqrt(w)
    __shared__ double posd[192], sig_s[64], dg_s[64], eneg_s[64];
    __shared__ double t0a_s[64], t0b_s[64], ga_s[64], gb_s[64];
    __shared__ double ua_s[64], ub_s[64];
    __shared__ double dinv_s[64], dvec_s[64];
    __shared__ double lam_sh, sw_sh;
    __shared__ int fl_w[4];

    double* const Cd0 = R;          // [64][66] f64, gram ping buffer
    double* const Cd1 = R + 64*66;  // [64][66] f64, gram pong buffer
    double* const SB = R;           // [64][66] f64, S (post-gram .. end)
    double* const Pm = R + 64*66;   // [64][66] f64, P = A*S

    const float* Tm = T + (size_t)m*64*512;
    const int srow = tid >> 4, sc4 = (tid & 15) * 4;

    // earliest possible chunk-0 prefetch
    float4 v = *(const float4*)&Tm[srow*512 + sc4];

    // ---- preamble: per-atom loads only (waves 4-6) ----
    if (tid >= 256 && tid < 320) {
        const int at = tid - 256;
        posd[3*at+0] = (double)pos[(m*64+at)*3+0];
        posd[3*at+1] = (double)pos[(m*64+at)*3+1];
        posd[3*at+2] = (double)pos[(m*64+at)*3+2];
        double r = (double)covr[an[m*64+at]];
        sig_s[at] = r*r;
        const float* np_ = nattr + (size_t)(m*64+at)*10;
        float best = np_[0]; int bi = 0;
        #pragma unroll
        for (int k = 1; k < 10; ++k) { float vv = np_[k]; if (vv > best) { best = vv; bi = k; } }
        dg_s[at] = (double)hard[bi] + 1.0/(SQRT_PI*r);
    } else if (tid >= 320 && tid < 384) {
        const int at = tid - 320;
        eneg_s[at] = (double)eneg[m*64 + at];
    }
    __syncthreads();   // atom data ready

    // ---- phase B: probe (waves 0-3) || edge weights (tid 256-767)
    //      || symmetric A-build (tid 256-1023, 3 triangle entries each) ----
    if (rg < 4) {
        const double af1 = (double)(jl + 1),  bf1 = (double)(jl + 65);
        const double af2 = (double)(1 + ((jl*7 + 3) % 61));
        const double bf2 = (double)(2 + ((jl*13 + 5) % 53));
        dbl4 c1 = {0.0,0.0,0.0,0.0}, c2 = {0.0,0.0,0.0,0.0};
        c1 = __builtin_amdgcn_mfma_f64_16x16x4f64(af1, bf1, c1, 0, 0, 0);
        c2 = __builtin_amdgcn_mfma_f64_16x16x4f64(af2, bf2, c2, 0, 0, 0);
        int myh = -1;
        for (int hh = 0; hh < 8; ++hh) {
            const int h = rg*8 + hh;
            const int pS = h >> 4, pA = (h >> 3) & 1, pB = (h >> 2) & 1, pD = h & 3;
            bool ok = true;
            #pragma unroll
            for (int r = 0; r < 4; ++r) {
                int row, col;
                const int v0 = 4*kl + r, v1 = kl + 4*r;
                if (pD == 0)      { row = v0; col = ml; }
                else if (pD == 1) { row = v1; col = ml; }
                else if (pD == 2) { row = ml; col = v0; }
                else              { row = ml; col = v1; }
                double r1 = 0.0, r2 = 0.0;
                #pragma unroll
                for (int k = 0; k < 4; ++k) {
                    const int la = pA ? (row*4 + k) : (row + 16*k);
                    const int lb = pB ? (col*4 + k) : (col + 16*k);
                    if (pS == 0) {
                        r1 += (double)(la + 1) * (double)(lb + 65);
                        r2 += (double)(1 + ((la*7+3) % 61)) * (double)(2 + ((lb*13+5) % 53));
                    } else {
                        r1 += (double)(lb + 1) * (double)(la + 65);
                        r2 += (double)(1 + ((lb*7+3) % 61)) * (double)(2 + ((la*13+5) % 53));
                    }
                }
                if (c1[r] != r1 || c2[r] != r2) ok = false;
            }
            if (__ballot(ok) == ~0ull) myh = h;
        }
        if (jl == 0) fl_w[rg] = myh;
    } else {
        if (tid < 768) {
            const int e = tid - 256;
            const int a0 = eidx[(size_t)m*1024 + e];
            const int a1 = eidx[(size_t)m*1024 + 512 + e];
            double dx = posd[3*a0+0]-posd[3*a1+0];
            double dy = posd[3*a0+1]-posd[3*a1+1];
            double dz = posd[3*a0+2]-posd[3*a1+2];
            double d  = sqrt(dx*dx+dy*dy+dz*dz);
            double w  = 1.0 / (1.0/cos(PI_OVER_2RC*d) - 1.0);
            w_sl[e]  = w;
            rw_sl[e] = sqrt(w);
        }
        // lower triangle: 2080 entries over 768 threads, 3 rounds, mirror-write
        #pragma unroll
        for (int q = 0; q < 3; ++q) {
            const int t = (tid - 256) + q*768;
            if (t < 2080) {
                int i = (int)((sqrt(8.0*(double)t + 1.0) - 1.0) * 0.5);
                if ((i+1)*(i+2)/2 <= t) ++i;     // fix sqrt rounding
                if (i*(i+1)/2 > t) --i;
                const int j = t - i*(i+1)/2;     // j <= i
                double av = a_entry(i, j, posd, sig_s, dg_s);
                AB[i*65 + j] = av;
                AB[j*65 + i] = av;
            }
        }
    }
    __syncthreads();   // fl_w + w/rw + A visible

    // layout constants (every thread)
    int hbest = max(max(fl_w[0], fl_w[1]), max(fl_w[2], fl_w[3]));
    if (hbest < 0) hbest = 1;   // unreachable on gfx950; standard-layout guess
    const int cS = hbest >> 4, cA = (hbest >> 3) & 1, cB = (hbest >> 2) & 1, cD = hbest & 3;
    const int aRow = cA ? (jl >> 2) : ml;
    const int aK   = cA ? (jl & 3)  : kl;
    const int bRow = cB ? (jl >> 2) : ml;
    const int bK   = cB ? (jl & 3)  : kl;
    int drow[4], dcol[4];
    #pragma unroll
    for (int r = 0; r < 4; ++r) {
        const int v0 = 4*kl + r, v1 = kl + 4*r;
        if (cD == 0)      { drow[r] = v0; dcol[r] = ml; }
        else if (cD == 1) { drow[r] = v1; dcol[r] = ml; }
        else if (cD == 2) { drow[r] = ml; dcol[r] = v0; }
        else              { drow[r] = ml; dcol[r] = v1; }
    }

    // ---- Gram work assignment: 10 tiles, diag waves {0,5,10,15} full-k,
    //      off-diag pairs split by k-range. wm: 0=kk 0..15, 1=kk 0..7, 2=kk 8..15.
    int tp, tq, wm;
    switch (rg) {
        case 0:  tp=0; tq=0; wm=0; break;
        case 5:  tp=1; tq=1; wm=0; break;
        case 10: tp=2; tq=2; wm=0; break;
        case 15: tp=3; tq=3; wm=0; break;
        case 1:  tp=1; tq=0; wm=1; break;
        case 2:  tp=1; tq=0; wm=2; break;
        case 3:  tp=2; tq=0; wm=1; break;
        case 4:  tp=2; tq=0; wm=2; break;
        case 6:  tp=2; tq=1; wm=1; break;
        case 7:  tp=2; tq=1; wm=2; break;
        case 8:  tp=3; tq=0; wm=1; break;
        case 9:  tp=3; tq=0; wm=2; break;
        case 11: tp=3; tq=1; wm=1; break;
        case 12: tp=3; tq=1; wm=2; break;
        case 13: tp=3; tq=2; wm=1; break;
        default: tp=3; tq=2; wm=2; break;   // rg == 14
    }
    const double* ca_b = &Cd0[(size_t)(tp*16 + aRow)*66 + aK];
    const double* cb_b = &Cd0[(size_t)(tq*16 + bRow)*66 + bK];
    dbl4 vacc = {0.0, 0.0, 0.0, 0.0};
    double t0b_p = 0.0;

    // ---- prologue: stage chunk 0 into Cd0, prefetch chunk 1 ----
    {
        const double r0 = rw_sl[sc4+0], r1 = rw_sl[sc4+1];
        const double r2 = rw_sl[sc4+2], r3 = rw_sl[sc4+3];
        const double c0 = (double)v.x*r0, c1 = (double)v.y*r1;
        const double c2 = (double)v.z*r2, c3 = (double)v.w*r3;
        double2 p0; p0.x = c0; p0.y = c1;
        double2 p1; p1.x = c2; p1.y = c3;
        *(double2*)&Cd0[srow*66 + sc4]     = p0;
        *(double2*)&Cd0[srow*66 + sc4 + 2] = p1;
        t0b_p += c0*r0 + c1*r1 + c2*r2 + c3*r3;
        v = *(const float4*)&Tm[srow*512 + 64 + sc4];
    }
    __syncthreads();   // Cd0 (chunk 0) visible

    #pragma unroll 1
    for (int cc = 0; cc < 8; ++cc) {
        // stage chunk cc+1 into the other buffer (overlaps this chunk's MFMA)
        if (cc < 7) {
            const int e = (cc+1)*64 + sc4;
            const double r0 = rw_sl[e+0], r1 = rw_sl[e+1];
            const double r2 = rw_sl[e+2], r3 = rw_sl[e+3];
            const double c0 = (double)v.x*r0, c1 = (double)v.y*r1;
            const double c2 = (double)v.z*r2, c3 = (double)v.w*r3;
            double* Cw = (((cc+1) & 1) ? Cd1 : Cd0);
            double2 p0; p0.x = c0; p0.y = c1;
            double2 p1; p1.x = c2; p1.y = c3;
            *(double2*)&Cw[srow*66 + sc4]     = p0;
            *(double2*)&Cw[srow*66 + sc4 + 2] = p1;
            t0b_p += c0*r0 + c1*r1 + c2*r2 + c3*r3;
            if (cc < 6) v = *(const float4*)&Tm[srow*512 + (cc+2)*64 + sc4];
        }
        if (cc == 0 && tid >= 128 && tid < 192) {  // wave2: sum(w) (cheap, once)
            const int ll = tid - 128;
            double s = 0.0;
            #pragma unroll
            for (int c = 0; c < 8; ++c) s += w_sl[c*64 + ll];
            #pragma unroll
            for (int off = 32; off > 0; off >>= 1) s += __shfl_down(s, off);
            if (ll == 0) sw_sh = s;
        }
        const int bo = (cc & 1) * 4224;            // current buffer offset (elements)
        if (wm == 0) {
            #pragma unroll
            for (int kk = 0; kk < 16; ++kk)
                vacc = mfma64(cS, ca_b[bo + kk*4], cb_b[bo + kk*4], vacc);
        } else if (wm == 1) {
            #pragma unroll
            for (int kk = 0; kk < 8; ++kk)
                vacc = mfma64(cS, ca_b[bo + kk*4], cb_b[bo + kk*4], vacc);
        } else {
            #pragma unroll
            for (int kk = 8; kk < 16; ++kk)
                vacc = mfma64(cS, ca_b[bo + kk*4], cb_b[bo + kk*4], vacc);
        }
        __syncthreads();   // reads of buf[cc&1] done; staged chunk cc+1 visible
    }
    // last loop barrier doubles as the gram->SB transition barrier

    // ---- S assembly: full/first-half writers first, second-half adders second ----
    if (wm != 2) {
        #pragma unroll
        for (int r = 0; r < 4; ++r) {
            const int ri = tp*16 + drow[r], cj = tq*16 + dcol[r];
            SB[ri*66 + cj] = vacc[r];
            if (tp != tq) SB[cj*66 + ri] = vacc[r];
        }
    }
    {   // t0b: reduce 16 column-group partials per row (register-only)
        double t = t0b_p;
        t += __shfl_down(t, 8, 16);
        t += __shfl_down(t, 4, 16);
        t += __shfl_down(t, 2, 16);
        t += __shfl_down(t, 1, 16);
        if ((tid & 15) == 0) t0b_s[tid >> 4] = t;
    }
    __syncthreads();
    if (wm == 2) {
        #pragma unroll
        for (int r = 0; r < 4; ++r) {
            const int ri = tp*16 + drow[r], cj = tq*16 + dcol[r];
            const double vv = vacc[r];
            SB[ri*66 + cj] += vv;
            if (tp != tq) SB[cj*66 + ri] += vv;
        }
    }
    __syncthreads();   // S complete

    // ---- t0a = -S·eneg (LDS-S, 16-lane reduce) ----
    {
        const int c16 = tid & 15, row16 = tid >> 4;
        double a = 0.0;
        #pragma unroll
        for (int kk = 0; kk < 4; ++kk)
            a += SB[row16*66 + 4*c16 + kk] * eneg_s[4*c16 + kk];
        a += __shfl_down(a, 8, 16);
        a += __shfl_down(a, 4, 16);
        a += __shfl_down(a, 2, 16);
        a += __shfl_down(a, 1, 16);
        if (c16 == 0) t0a_s[row16] = -a;
    }
    __syncthreads();

    // ---- g = A·t0 via wave reduction (A-column read from LDS) ----
    {
        const double areg0 = AB[(rg+ 0)*65 + jl];
        const double areg1 = AB[(rg+16)*65 + jl];
        const double areg2 = AB[(rg+32)*65 + jl];
        const double areg3 = AB[(rg+48)*65 + jl];
        const double ta = t0a_s[jl], tb = t0b_s[jl];
        double ra0 = areg0*ta, ra1 = areg1*ta, ra2 = areg2*ta, ra3 = areg3*ta;
        double rb0 = areg0*tb, rb1 = areg1*tb, rb2 = areg2*tb, rb3 = areg3*tb;
        #pragma unroll
        for (int off = 32; off > 0; off >>= 1) {
            ra0 += __shfl_down(ra0, off); ra1 += __shfl_down(ra1, off);
            ra2 += __shfl_down(ra2, off); ra3 += __shfl_down(ra3, off);
            rb0 += __shfl_down(rb0, off); rb1 += __shfl_down(rb1, off);
            rb2 += __shfl_down(rb2, off); rb3 += __shfl_down(rb3, off);
        }
        if (jl == 0) {
            ga_s[rg+ 0] = ra0; ga_s[rg+16] = ra1; ga_s[rg+32] = ra2; ga_s[rg+48] = ra3;
            gb_s[rg+ 0] = rb0; gb_s[rg+16] = rb1; gb_s[rg+32] = rb2; gb_s[rg+48] = rb3;
        }
    }
    __syncthreads();

    // ---- GEMM1: P = A·S (16 tiles / 16 waves, immediate-offset operands) ----
    const int ti = rg >> 2, tj = rg & 3;
    {
        const double* xb = &AB[(size_t)(ti*16 + aRow)*65 + aK];
        const double* yb = &SB[(size_t)bK*66 + tj*16 + bRow];
        dbl4 pacc = {0.0, 0.0, 0.0, 0.0};
        #pragma unroll
        for (int kk = 0; kk < 16; ++kk)
            pacc = mfma64(cS, xb[kk*4], yb[kk*264], pacc);
        #pragma unroll
        for (int r = 0; r < 4; ++r)
            Pm[(ti*16 + drow[r])*66 + tj*16 + dcol[r]] = pacc[r];   // Pm != SB, no barrier needed
    }
    __syncthreads();   // P visible

    // ---- GEMM2: M = A + P·A, overwrite AB ----
    {
        dbl4 macc;
        #pragma unroll
        for (int r = 0; r < 4; ++r)
            macc[r] = AB[(ti*16 + drow[r])*65 + tj*16 + dcol[r]];
        const double* xb = &Pm[(size_t)(ti*16 + aRow)*66 + aK];
        const double* yb = &AB[(size_t)bK*65 + tj*16 + bRow];
        #pragma unroll
        for (int kk = 0; kk < 16; ++kk)
            macc = mfma64(cS, xb[kk*4], yb[kk*260], macc);
        __syncthreads();   // all GEMM2 AB reads done
        #pragma unroll
        for (int r = 0; r < 4; ++r)
            AB[(ti*16 + drow[r])*65 + tj*16 + dcol[r]] = macc[r];
    }
    __syncthreads();

    // ---- blocked LDL^T: wave0 panel factor + trailing updates (verified) ----
    for (int pb = 0; pb < 4; ++pb) {
        const int kb = pb*16;
        if (tid < 64) {
            const int i = tid;
            double pr[16];
            #pragma unroll
            for (int c = 0; c < 16; ++c) pr[c] = AB[i*65 + kb + c];
            #pragma unroll
            for (int c = 0; c < 16; ++c) {
                const int k = kb + c;
                const double Dk = bcast64(pr[c], k);
                const double di = 1.0 / Dk;
                if (i == k) { dinv_s[k] = di; dvec_s[k] = Dk; }
                const double lik = pr[c] * di;
                #pragma unroll
                for (int j = c+1; j < 16; ++j) {
                    const double mkj = bcast64(pr[j], k);
                    if (i > k) pr[j] -= lik * mkj;
                }
                if (i > k) pr[c] = lik;
            }
            #pragma unroll
            for (int c = 0; c < 16; ++c) AB[i*65 + kb + c] = pr[c];
        }
        __syncthreads();
        const int lim = kb + 16;
        if (lim < 64) {
            double tacc[4] = {0.0, 0.0, 0.0, 0.0};
            #pragma unroll 4
            for (int c = 0; c < 16; ++c) {
                double lbv = AB[jl*65 + kb + c] * dvec_s[kb + c];
                #pragma unroll
                for (int p = 0; p < 4; ++p)
                    tacc[p] += AB[(rg+16*p)*65 + kb + c] * lbv;
            }
            if (jl >= lim) {
                #pragma unroll
                for (int p = 0; p < 4; ++p) {
                    int i = rg + 16*p;
                    if (i >= lim) AB[i*65 + jl] -= tacc[p];
                }
            }
        }
        __syncthreads();
    }

    // ---- solves: wave0 does RHS a, wave1 does RHS b (independent chains) ----
    if (tid < 128) {
        const int i = jl;
        double h = (rg == 0) ? ga_s[i] : gb_s[i];
        #pragma unroll
        for (int j = 0; j < 63; ++j) {
            double x = bcast64(h, j);
            double lij = (i > j) ? AB[i*65+j] : 0.0;
            h -= lij*x;
        }
        h *= dinv_s[i];
        #pragma unroll
        for (int j = 63; j > 0; --j) {
            double x = bcast64(h, j);
            double lji = (i < j) ? AB[j*65+i] : 0.0;
            h -= lji*x;
        }
        if (rg == 0) ua_s[i] = h; else ub_s[i] = h;
    }
    __syncthreads();

    // ---- lambda (identities: sa.t0b = ua.gb, sb.t0b = ub.gb), via lam_sh ----
    if (tid < 64) {
        const double ua = ua_s[tid], ub = ub_s[tid], gbv = gb_s[tid];
        double d1 = eneg_s[tid]*t0b_s[tid] + ua*gbv;   // = (eneg + sa)·t0b termwise
        double d2 = ub*gbv;                            // = sb·t0b termwise
        #pragma unroll
        for (int off = 32; off > 0; off >>= 1) {
            d1 += __shfl_down(d1, off);
            d2 += __shfl_down(d2, off);
        }
        if (tid == 0) {
            double sY = -d1;
            double sZ = sw_sh - d2;
            lam_sh = ((double)qtot[m] - sY) / (1.0 - sZ);
        }
    }
    __syncthreads();
    if (tid < 64)
        outp[m*64 + tid] = (float)(ua_s[tid] - lam_sh*ub_s[tid]);
}

extern "C" void kernel_launch(void* const* d_in, const int* in_sizes, int n_in,
                              void* d_out, int out_size, void* d_ws, size_t ws_size,
                              hipStream_t stream) {
    const float* pos  = (const float*)d_in[0];
    const float* T    = (const float*)d_in[1];
    const float* eneg = (const float*)d_in[2];
    const float* nat  = (const float*)d_in[3];
    const float* qt   = (const float*)d_in[4];
    // d_in[5] 'p' unused
    const float* hard = (const float*)d_in[6];
    const float* covr = (const float*)d_in[7];
    const int*   an   = (const int*)d_in[8];
    const int*   eidx = (const int*)d_in[9];
    float* outp = (float*)d_out;
    (void)n_in; (void)out_size; (void)d_ws; (void)ws_size;

    const int B = in_sizes[4];
    k_fused<<<dim3(B), dim3(1024), 0, stream>>>(pos, T, eidx, nat, eneg, qt,
                                                hard, covr, an, outp);
}